// Round 4
// baseline (7721.414 us; speedup 1.0000x reference)
//
#include <hip/hip_runtime.h>
#include <math.h>

#define T_STEPS 100
#define B_DIM 128
#define I_DIM 1024
#define H_DIM 4096
#define O_DIM 512
#define T_CHUNK 20
#define NBLK 256

typedef _Float16 f16x8 __attribute__((ext_vector_type(8)));
typedef float    f32x4 __attribute__((ext_vector_type(4)));

__device__ __forceinline__ unsigned fmap(float f){
  unsigned u = __float_as_uint(f);
  return (u & 0x80000000u) ? ~u : (u | 0x80000000u);
}
__device__ __forceinline__ float funmap(unsigned m){
  unsigned u = (m & 0x80000000u) ? (m & 0x7FFFFFFFu) : ~m;
  return __uint_as_float(u);
}
__device__ __forceinline__ float vth_of(unsigned m){
  return 0.3f * tanhf(0.3f * funmap(m));
}

// Monotonic-counter grid barrier. Correct under overshoot (cnt only grows).
// Cross-XCD visibility via __threadfence (wbL2/invL2) — validated by R1's
// ticket protocol on this chip. Co-residency by capacity: 256 blocks,
// 18.4KB LDS, 256 thr -> >=4 blocks/CU capacity, all blocks resident.
__device__ __forceinline__ void gbar(unsigned* cnt, unsigned target){
  __syncthreads();
  if (threadIdx.x == 0){
    __threadfence();
    atomicAdd(cnt, 1u);
    while (__hip_atomic_load(cnt, __ATOMIC_RELAXED, __HIP_MEMORY_SCOPE_AGENT) < target)
      __builtin_amdgcn_s_sleep(2);
    __threadfence();
  }
  __syncthreads();
}

__global__ __launch_bounds__(256) void init_kernel(
    float* hv, float* ovB, float* out,
    unsigned* hmaxA, unsigned* omaxA, unsigned* cnts)
{
  int i = blockIdx.x * 256 + threadIdx.x;
  if (i < B_DIM*H_DIM) hv[i] = 0.f;
  if (i < B_DIM*O_DIM) { ovB[i] = 0.f; out[i] = 0.f; }
  if (i < 16) cnts[i] = 0u;
  if (i < 128) {
    unsigned v = (i==0) ? 0x80000000u : fmap(-3.0e38f);  // slot0 = max(zero state)
    hmaxA[i] = v; omaxA[i] = v;
  }
}

// spike_data [B][I][T] fp32 -> fragment-block-tiled f16 hi/lo of (x*2048).
__global__ __launch_bounds__(256) void prep_x(const float* __restrict__ sp,
                                              _Float16* __restrict__ Ahi,
                                              _Float16* __restrict__ Alo)
{
  __shared__ float tile[32][16][10];
  const int b16 = blockIdx.x, kc = blockIdx.y, tc = blockIdx.z;
  for (int e = threadIdx.x; e < 5120; e += 256){
    int tt = e % 10, row = e / 10;
    int bb = row >> 5, ii = row & 31;
    tile[ii][bb][tt] =
      sp[((size_t)(b16*16+bb)*I_DIM + kc*32 + ii)*T_STEPS + tc*10 + tt];
  }
  __syncthreads();
  for (int u = threadIdx.x; u < 640; u += 256){
    int tl = u >> 6, l = u & 63, kg = l >> 4, r = l & 15;
    f16x8 hi, lo;
    #pragma unroll
    for (int e=0;e<8;e++){
      float x = tile[kg*8+e][r][tl] * 2048.f;
      _Float16 h = (_Float16)x;
      hi[e] = h;
      lo[e] = (_Float16)(x - (float)h);
    }
    int t = tc*10 + tl;
    size_t off = ((size_t)(t*8 + b16)*32 + kc)*512 + kg*128 + r*8;
    *(f16x8*)(Ahi + off) = hi;
    *(f16x8*)(Alo + off) = lo;
  }
}

// Wh [H][I] fp32 -> FB-tiled f16 hi/lo of (w*256).
__global__ __launch_bounds__(256) void prep_w(const float* __restrict__ Wh,
                                              _Float16* __restrict__ Bhi,
                                              _Float16* __restrict__ Blo)
{
  const int n16 = blockIdx.x;
  for (int u = threadIdx.x; u < 2048; u += 256){
    int kc = u >> 6, l = u & 63, kg = l >> 4, r = l & 15;
    const float* src = Wh + (size_t)(n16*16 + r)*I_DIM + kc*32 + kg*8;
    f16x8 hi, lo;
    #pragma unroll
    for (int e=0;e<8;e++){
      float x = src[e] * 256.f;
      _Float16 h = (_Float16)x;
      hi[e] = h;
      lo[e] = (_Float16)(x - (float)h);
    }
    size_t off = ((size_t)n16*32 + kc)*512 + kg*128 + r*8;
    *(f16x8*)(Bhi + off) = hi;
    *(f16x8*)(Blo + off) = lo;
  }
}

// Batched GEMM1 via fp16x3 exact-split MFMA. 128x128 C-tile, 4 waves 2x2.
// Epilogue stages C through LDS for coalesced 256B row-segment stores.
__global__ __launch_bounds__(256) void gemm1_mfma(
    const _Float16* __restrict__ Ahi, const _Float16* __restrict__ Alo,
    const _Float16* __restrict__ Bhi, const _Float16* __restrict__ Blo,
    float* __restrict__ G, int t0)
{
  __shared__ __align__(16) _Float16 lds[4][8][512];
  const int tid = threadIdx.x, wave = tid>>6, lane = tid&63;
  const int bn = blockIdx.x, bm = blockIdx.y;
  const int m16b = (t0+bm)*8, n16b = bn*8;
  const int wm = wave>>1, wn = wave&1;

  const _Float16* srcbase = (wave==0)?Ahi:(wave==1)?Alo:(wave==2)?Bhi:Blo;
  const int r16b = (wave<2) ? m16b : n16b;

  f32x4 acc[16];
  #pragma unroll
  for (int i=0;i<16;i++) acc[i] = (f32x4){0.f,0.f,0.f,0.f};

  int4 rr[8];
  #pragma unroll
  for (int q=0;q<8;q++)
    rr[q] = *(const int4*)(srcbase + ((size_t)(r16b+q)*32)*512 + lane*8);

  for (int kc=0;kc<32;kc++){
    __syncthreads();
    #pragma unroll
    for (int q=0;q<8;q++) *(int4*)&lds[wave][q][lane*8] = rr[q];
    __syncthreads();
    if (kc < 31){
      #pragma unroll
      for (int q=0;q<8;q++)
        rr[q] = *(const int4*)(srcbase + ((size_t)(r16b+q)*32 + kc+1)*512 + lane*8);
    }
    f16x8 fAh[4], fAl[4], fBh[4], fBl[4];
    #pragma unroll
    for (int i=0;i<4;i++){
      fAh[i] = *(const f16x8*)&lds[0][wm*4+i][lane*8];
      fAl[i] = *(const f16x8*)&lds[1][wm*4+i][lane*8];
      fBh[i] = *(const f16x8*)&lds[2][wn*4+i][lane*8];
      fBl[i] = *(const f16x8*)&lds[3][wn*4+i][lane*8];
    }
    #pragma unroll
    for (int i=0;i<4;i++)
      #pragma unroll
      for (int j=0;j<4;j++)
        acc[i*4+j] = __builtin_amdgcn_mfma_f32_16x16x32_f16(fAh[i], fBh[j], acc[i*4+j], 0,0,0);
    #pragma unroll
    for (int i=0;i<4;i++)
      #pragma unroll
      for (int j=0;j<4;j++)
        acc[i*4+j] = __builtin_amdgcn_mfma_f32_16x16x32_f16(fAh[i], fBl[j], acc[i*4+j], 0,0,0);
    #pragma unroll
    for (int i=0;i<4;i++)
      #pragma unroll
      for (int j=0;j<4;j++)
        acc[i*4+j] = __builtin_amdgcn_mfma_f32_16x16x32_f16(fAl[i], fBh[j], acc[i*4+j], 0,0,0);
  }
  // Coalesced epilogue via LDS: per wave a 32x64 half-quadrant at a time.
  const int colw = lane&15, quad = lane>>4;
  const float sc = 1.f/(2048.f*256.f);
  float* eds = (float*)lds + wave*2048;   // 32 rows x 64 cols
  __syncthreads();                         // staging no longer needed
  #pragma unroll
  for (int ih=0; ih<2; ih++){
    #pragma unroll
    for (int il=0; il<2; il++){
      int i = ih*2+il;
      #pragma unroll
      for (int j=0;j<4;j++)
        #pragma unroll
        for (int r=0;r<4;r++)
          eds[(il*16 + quad*4 + r)*64 + j*16 + colw] = acc[i*4+j][r]*sc;
    }
    #pragma unroll
    for (int rr8=0; rr8<8; rr8++){
      int row = rr8*4 + quad;
      float4 v = *(float4*)&eds[row*64 + colw*4];
      int m = bm*128 + wm*64 + ih*32 + row;
      int n = bn*128 + wn*64 + colw*4;
      *(float4*)&G[(size_t)m*H_DIM + n] = v;
    }
  }
}

// Persistent 20-step recurrence kernel, 256 blocks.
// Per step: phase1 (hv update + hmax + ov_{t-1} max-scan + zero ov_t) | gbar |
//           phase2 (GEMM2: spike(hv_t)@Wo^T + decay base + out accum) | gbar.
__global__ __launch_bounds__(256) void coop_steps(
    const float* __restrict__ G,
    float* __restrict__ hv,
    float* __restrict__ ovA, float* __restrict__ ovB,
    const float* __restrict__ Wo,
    unsigned* __restrict__ hmaxA, unsigned* __restrict__ omaxA,
    unsigned* __restrict__ cnt,
    float* __restrict__ out,
    int t0, int nsteps, int last)
{
  __shared__ float As[32][68], Bs[32][68];
  __shared__ float red[256];
  const int tid = threadIdx.x, blk = blockIdx.x;
  unsigned bar = 0;

  for (int s = 0; s < nsteps; s++){
    const int t = t0 + s;
    float* ovCur  = (t&1) ? ovB : ovA;
    float* ovPrev = (t&1) ? ovA : ovB;

    { // ---- phase 1 ----
      const float vthH = vth_of(hmaxA[t]);
      const float* Gs = G + (size_t)s*B_DIM*H_DIM;
      float lmax = -3.0e38f;
      #pragma unroll
      for (int q=0;q<2;q++){
        int f4 = blk*512 + q*256 + tid;
        float4 h = *(const float4*)(hv + (size_t)f4*4);
        float4 g = *(const float4*)(Gs + (size_t)f4*4);
        float4 o;
        o.x = (h.x>vthH ? 0.f : 0.5f*h.x) + g.x;
        o.y = (h.y>vthH ? 0.f : 0.5f*h.y) + g.y;
        o.z = (h.z>vthH ? 0.f : 0.5f*h.z) + g.z;
        o.w = (h.w>vthH ? 0.f : 0.5f*h.w) + g.w;
        *(float4*)(hv + (size_t)f4*4) = o;
        lmax = fmaxf(lmax, fmaxf(fmaxf(o.x,o.y),fmaxf(o.z,o.w)));
      }
      red[tid]=lmax; __syncthreads();
      for (int r=128;r>0;r>>=1){ if (tid<r) red[tid]=fmaxf(red[tid],red[tid+r]); __syncthreads(); }
      if (tid==0) atomicMax(&hmaxA[t+1], fmap(red[0]));
      float om = -3.0e38f;
      if (tid < 64){
        int f4 = blk*64 + tid;
        float4 p = *(const float4*)(ovPrev + (size_t)f4*4);
        om = fmaxf(fmaxf(p.x,p.y),fmaxf(p.z,p.w));
        *(float4*)(ovCur + (size_t)f4*4) = make_float4(0.f,0.f,0.f,0.f);
      }
      __syncthreads();
      red[tid]=om; __syncthreads();
      for (int r=128;r>0;r>>=1){ if (tid<r) red[tid]=fmaxf(red[tid],red[tid+r]); __syncthreads(); }
      if (tid==0) atomicMax(&omaxA[t], fmap(red[0]));
    }
    gbar(cnt, (++bar)*NBLK);

    { // ---- phase 2: GEMM2, 16 tiles x 16 K-chunks ----
      const float vth1 = vth_of(hmaxA[t+1]);
      const float vthO = vth_of(omaxA[t]);
      const int kc = blk>>4, mb = (blk>>3)&1, nb = blk&7;
      const float* Ap = hv + (size_t)(mb*64)*H_DIM + kc*256;
      const float* Bp = Wo + (size_t)(nb*64)*H_DIM + kc*256;
      const int lrow = tid>>2, lk = (tid&3)<<2;
      const float* Arow = Ap + (size_t)lrow*H_DIM + lk;
      const float* Brow = Bp + (size_t)lrow*H_DIM + lk;

      float4 a0 = *(const float4*)(Arow);
      float4 a1 = *(const float4*)(Arow + 16);
      float4 b0 = *(const float4*)(Brow);
      float4 b1 = *(const float4*)(Brow + 16);

      const int tx = tid&15, ty = tid>>4;
      float acc[4][4];
      #pragma unroll
      for (int r=0;r<4;r++){ acc[r][0]=0.f; acc[r][1]=0.f; acc[r][2]=0.f; acc[r][3]=0.f; }

      for (int s2=0;s2<8;s2++){
        a0.x=(a0.x>vth1)?1.f:0.f; a0.y=(a0.y>vth1)?1.f:0.f;
        a0.z=(a0.z>vth1)?1.f:0.f; a0.w=(a0.w>vth1)?1.f:0.f;
        a1.x=(a1.x>vth1)?1.f:0.f; a1.y=(a1.y>vth1)?1.f:0.f;
        a1.z=(a1.z>vth1)?1.f:0.f; a1.w=(a1.w>vth1)?1.f:0.f;
        __syncthreads();
        As[lk+0 ][lrow]=a0.x; As[lk+1 ][lrow]=a0.y; As[lk+2 ][lrow]=a0.z; As[lk+3 ][lrow]=a0.w;
        As[lk+16][lrow]=a1.x; As[lk+17][lrow]=a1.y; As[lk+18][lrow]=a1.z; As[lk+19][lrow]=a1.w;
        Bs[lk+0 ][lrow]=b0.x; Bs[lk+1 ][lrow]=b0.y; Bs[lk+2 ][lrow]=b0.z; Bs[lk+3 ][lrow]=b0.w;
        Bs[lk+16][lrow]=b1.x; Bs[lk+17][lrow]=b1.y; Bs[lk+18][lrow]=b1.z; Bs[lk+19][lrow]=b1.w;
        __syncthreads();
        if (s2 < 7){
          const float* An = Arow + (s2+1)*32;
          const float* Bn = Brow + (s2+1)*32;
          a0 = *(const float4*)(An); a1 = *(const float4*)(An+16);
          b0 = *(const float4*)(Bn); b1 = *(const float4*)(Bn+16);
        }
        #pragma unroll
        for (int k=0;k<32;k++){
          float4 a = *(const float4*)&As[k][ty<<2];
          float4 b = *(const float4*)&Bs[k][tx<<2];
          acc[0][0] += a.x*b.x; acc[0][1] += a.x*b.y; acc[0][2] += a.x*b.z; acc[0][3] += a.x*b.w;
          acc[1][0] += a.y*b.x; acc[1][1] += a.y*b.y; acc[1][2] += a.y*b.z; acc[1][3] += a.y*b.w;
          acc[2][0] += a.z*b.x; acc[2][1] += a.z*b.y; acc[2][2] += a.z*b.z; acc[2][3] += a.z*b.w;
          acc[3][0] += a.w*b.x; acc[3][1] += a.w*b.y; acc[3][2] += a.w*b.z; acc[3][3] += a.w*b.w;
        }
      }

      const int r0 = mb*64 + (ty<<2);
      const int c0 = nb*64 + (tx<<2);
      if (kc==0){
        #pragma unroll
        for (int r=0;r<4;r++)
          #pragma unroll
          for (int c=0;c<4;c++){
            size_t idx = (size_t)(r0+r)*O_DIM + c0+c;
            float o0 = ovPrev[idx];
            float os = (o0 > vthO) ? 1.f : 0.f;
            acc[r][c] += 0.5f*o0*(1.f-os);
            out[idx] += os;
          }
      }
      #pragma unroll
      for (int r=0;r<4;r++)
        #pragma unroll
        for (int c=0;c<4;c++)
          atomicAdd(&ovCur[(size_t)(r0+r)*O_DIM + c0+c], acc[r][c]);
    }
    gbar(cnt, (++bar)*NBLK);
  }

  if (last){
    // omax of ov_{T-1} (T-1 odd -> ovB), then out += spike(ov_{T-1}).
    float om = -3.0e38f;
    if (tid < 64){
      int f4 = blk*64 + tid;
      float4 p = *(const float4*)(ovB + (size_t)f4*4);
      om = fmaxf(fmaxf(p.x,p.y),fmaxf(p.z,p.w));
    }
    red[tid]=om; __syncthreads();
    for (int r=128;r>0;r>>=1){ if (tid<r) red[tid]=fmaxf(red[tid],red[tid+r]); __syncthreads(); }
    if (tid==0) atomicMax(&omaxA[T_STEPS], fmap(red[0]));
    gbar(cnt, (++bar)*NBLK);
    const float vthF = vth_of(omaxA[T_STEPS]);
    if (tid < 64){
      int f4 = blk*64 + tid;
      float4 p = *(const float4*)(ovB + (size_t)f4*4);
      float4 o = *(float4*)(out + (size_t)f4*4);
      o.x += (p.x>vthF)?1.f:0.f; o.y += (p.y>vthF)?1.f:0.f;
      o.z += (p.z>vthF)?1.f:0.f; o.w += (p.w>vthF)?1.f:0.f;
      *(float4*)(out + (size_t)f4*4) = o;
    }
  }
}

extern "C" void kernel_launch(void* const* d_in, const int* in_sizes, int n_in,
                              void* d_out, int out_size, void* d_ws, size_t ws_size,
                              hipStream_t stream) {
  const float* spike = (const float*)d_in[0];
  const float* Wh    = (const float*)d_in[5];   // [H, I]
  const float* Wo    = (const float*)d_in[6];   // [O, H]
  float* out = (float*)d_out;

  char* ws = (char*)d_ws;
  size_t off = 0;
  _Float16* XAhi = (_Float16*)(ws+off); off += (size_t)T_STEPS*B_DIM*I_DIM*2;
  _Float16* XAlo = (_Float16*)(ws+off); off += (size_t)T_STEPS*B_DIM*I_DIM*2;
  _Float16* WHhi = (_Float16*)(ws+off); off += (size_t)H_DIM*I_DIM*2;
  _Float16* WHlo = (_Float16*)(ws+off); off += (size_t)H_DIM*I_DIM*2;
  float* G  = (float*)(ws+off);         off += (size_t)T_CHUNK*B_DIM*H_DIM*4;
  float* hv = (float*)(ws+off);         off += (size_t)B_DIM*H_DIM*4;
  float* ovA = (float*)(ws+off);        off += (size_t)B_DIM*O_DIM*4;
  float* ovB = (float*)(ws+off);        off += (size_t)B_DIM*O_DIM*4;
  unsigned* hmaxA = (unsigned*)(ws+off); off += 128*4;
  unsigned* omaxA = (unsigned*)(ws+off); off += 128*4;
  unsigned* cnts  = (unsigned*)(ws+off); off += 16*4;
  (void)ws_size; (void)in_sizes; (void)n_in; (void)out_size;

  init_kernel<<<(B_DIM*H_DIM+255)/256, 256, 0, stream>>>(
      hv, ovB, out, hmaxA, omaxA, cnts);
  prep_x<<<dim3(8,32,10), 256, 0, stream>>>(spike, XAhi, XAlo);
  prep_w<<<256, 256, 0, stream>>>(Wh, WHhi, WHlo);

  const int nchunks = T_STEPS / T_CHUNK;
  for (int c = 0; c < nchunks; c++){
    gemm1_mfma<<<dim3(32, T_CHUNK), 256, 0, stream>>>(XAhi, XAlo, WHhi, WHlo, G, c*T_CHUNK);
    coop_steps<<<NBLK, 256, 0, stream>>>(
        G, hv, ovA, ovB, Wo, hmaxA, omaxA, cnts + c, out,
        c*T_CHUNK, T_CHUNK, (c == nchunks-1) ? 1 : 0);
  }
}

// Round 5
// 3527.570 us; speedup vs baseline: 2.1889x; 2.1889x over previous
//
#include <hip/hip_runtime.h>
#include <math.h>

#define T_STEPS 100
#define B_DIM 128
#define I_DIM 1024
#define H_DIM 4096
#define O_DIM 512
#define T_CHUNK 20
#define HS_RING 21
#define HS_SLOT ((size_t)8*128*512)   // f16 per t-slot (8 m16-tiles x 128 kc x 512)

typedef _Float16 f16x8 __attribute__((ext_vector_type(8)));
typedef _Float16 f16x4 __attribute__((ext_vector_type(4)));
typedef float    f32x4 __attribute__((ext_vector_type(4)));

__device__ __forceinline__ unsigned fmap(float f){
  unsigned u = __float_as_uint(f);
  return (u & 0x80000000u) ? ~u : (u | 0x80000000u);
}
__device__ __forceinline__ float funmap(unsigned m){
  unsigned u = (m & 0x80000000u) ? (m & 0x7FFFFFFFu) : ~m;
  return __uint_as_float(u);
}
__device__ __forceinline__ float vth_of(unsigned m){
  return 0.3f * tanhf(0.3f * funmap(m));
}

__global__ __launch_bounds__(256) void init_kernel(float* hv, unsigned* hmaxA)
{
  int i = blockIdx.x * 256 + threadIdx.x;
  if (i < B_DIM*H_DIM) hv[i] = 0.f;
  if (i < 128) hmaxA[i] = (i==0) ? 0x80000000u : fmap(-3.0e38f); // slot0 = max(0)
}

// spike_data [B][I][T] fp32 -> fragment-tiled f16 hi/lo of (x*2048), chunk of 20 t.
__global__ __launch_bounds__(256) void prep_x(const float* __restrict__ sp,
                                              _Float16* __restrict__ Ahi,
                                              _Float16* __restrict__ Alo, int t0)
{
  __shared__ float tile[32][16][10];
  const int b16 = blockIdx.x, kc = blockIdx.y, tz = blockIdx.z;
  for (int e = threadIdx.x; e < 5120; e += 256){
    int tt = e % 10, row = e / 10;
    int bb = row >> 5, ii = row & 31;
    tile[ii][bb][tt] =
      sp[((size_t)(b16*16+bb)*I_DIM + kc*32 + ii)*T_STEPS + t0 + tz*10 + tt];
  }
  __syncthreads();
  for (int u = threadIdx.x; u < 640; u += 256){
    int tl = u >> 6, l = u & 63, kg = l >> 4, r = l & 15;
    f16x8 hi, lo;
    #pragma unroll
    for (int e=0;e<8;e++){
      float x = tile[kg*8+e][r][tl] * 2048.f;
      _Float16 h = (_Float16)x;
      hi[e] = h;
      lo[e] = (_Float16)(x - (float)h);
    }
    int t_local = tz*10 + tl;
    size_t off = ((size_t)(t_local*8 + b16)*32 + kc)*512 + kg*128 + r*8;
    *(f16x8*)(Ahi + off) = hi;
    *(f16x8*)(Alo + off) = lo;
  }
}

// Wh [H][I] fp32 -> FB-tiled f16 hi/lo of (w*256).
__global__ __launch_bounds__(256) void prep_w(const float* __restrict__ Wh,
                                              _Float16* __restrict__ Bhi,
                                              _Float16* __restrict__ Blo)
{
  const int n16 = blockIdx.x;
  for (int u = threadIdx.x; u < 2048; u += 256){
    int kc = u >> 6, l = u & 63, kg = l >> 4, r = l & 15;
    const float* src = Wh + (size_t)(n16*16 + r)*I_DIM + kc*32 + kg*8;
    f16x8 hi, lo;
    #pragma unroll
    for (int e=0;e<8;e++){
      float x = src[e] * 256.f;
      _Float16 h = (_Float16)x;
      hi[e] = h;
      lo[e] = (_Float16)(x - (float)h);
    }
    size_t off = ((size_t)n16*32 + kc)*512 + kg*128 + r*8;
    *(f16x8*)(Bhi + off) = hi;
    *(f16x8*)(Blo + off) = lo;
  }
}

// Wo [O][H] fp32 -> FB-tiled f16 hi/lo of (w*256). 128 kc over H.
__global__ __launch_bounds__(256) void prep_wo(const float* __restrict__ Wo,
                                               _Float16* __restrict__ Bhi,
                                               _Float16* __restrict__ Blo)
{
  const int n16 = blockIdx.x;   // 0..31
  for (int u = threadIdx.x; u < 8192; u += 256){
    int kc = u >> 6, l = u & 63, kg = l >> 4, r = l & 15;
    const float* src = Wo + (size_t)(n16*16 + r)*H_DIM + kc*32 + kg*8;
    f16x8 hi, lo;
    #pragma unroll
    for (int e=0;e<8;e++){
      float x = src[e] * 256.f;
      _Float16 h = (_Float16)x;
      hi[e] = h;
      lo[e] = (_Float16)(x - (float)h);
    }
    size_t off = ((size_t)(n16*128 + kc))*512 + kg*128 + r*8;
    *(f16x8*)(Bhi + off) = hi;
    *(f16x8*)(Blo + off) = lo;
  }
}

// Batched GEMM1 (chunk of 20 t): G = XT @ Wh^T via fp16x3 exact-split MFMA.
__global__ __launch_bounds__(256) void gemm1_mfma(
    const _Float16* __restrict__ Ahi, const _Float16* __restrict__ Alo,
    const _Float16* __restrict__ Bhi, const _Float16* __restrict__ Blo,
    float* __restrict__ G)
{
  __shared__ __align__(16) _Float16 lds[4][8][512];
  const int tid = threadIdx.x, wave = tid>>6, lane = tid&63;
  const int bn = blockIdx.x, bm = blockIdx.y;
  const int m16b = bm*8, n16b = bn*8;
  const int wm = wave>>1, wn = wave&1;

  const _Float16* srcbase = (wave==0)?Ahi:(wave==1)?Alo:(wave==2)?Bhi:Blo;
  const int r16b = (wave<2) ? m16b : n16b;

  f32x4 acc[16];
  #pragma unroll
  for (int i=0;i<16;i++) acc[i] = (f32x4){0.f,0.f,0.f,0.f};

  int4 rr[8];
  #pragma unroll
  for (int q=0;q<8;q++)
    rr[q] = *(const int4*)(srcbase + ((size_t)(r16b+q)*32)*512 + lane*8);

  for (int kc=0;kc<32;kc++){
    __syncthreads();
    #pragma unroll
    for (int q=0;q<8;q++) *(int4*)&lds[wave][q][lane*8] = rr[q];
    __syncthreads();
    if (kc < 31){
      #pragma unroll
      for (int q=0;q<8;q++)
        rr[q] = *(const int4*)(srcbase + ((size_t)(r16b+q)*32 + kc+1)*512 + lane*8);
    }
    f16x8 fAh[4], fAl[4], fBh[4], fBl[4];
    #pragma unroll
    for (int i=0;i<4;i++){
      fAh[i] = *(const f16x8*)&lds[0][wm*4+i][lane*8];
      fAl[i] = *(const f16x8*)&lds[1][wm*4+i][lane*8];
      fBh[i] = *(const f16x8*)&lds[2][wn*4+i][lane*8];
      fBl[i] = *(const f16x8*)&lds[3][wn*4+i][lane*8];
    }
    #pragma unroll
    for (int i=0;i<4;i++)
      #pragma unroll
      for (int j=0;j<4;j++)
        acc[i*4+j] = __builtin_amdgcn_mfma_f32_16x16x32_f16(fAh[i], fBh[j], acc[i*4+j], 0,0,0);
    #pragma unroll
    for (int i=0;i<4;i++)
      #pragma unroll
      for (int j=0;j<4;j++)
        acc[i*4+j] = __builtin_amdgcn_mfma_f32_16x16x32_f16(fAh[i], fBl[j], acc[i*4+j], 0,0,0);
    #pragma unroll
    for (int i=0;i<4;i++)
      #pragma unroll
      for (int j=0;j<4;j++)
        acc[i*4+j] = __builtin_amdgcn_mfma_f32_16x16x32_f16(fAl[i], fBh[j], acc[i*4+j], 0,0,0);
  }
  const int colw = lane&15, quad = lane>>4;
  const float sc = 1.f/(2048.f*256.f);
  float* eds = (float*)lds + wave*2048;
  __syncthreads();
  #pragma unroll
  for (int ih=0; ih<2; ih++){
    #pragma unroll
    for (int il=0; il<2; il++){
      int i = ih*2+il;
      #pragma unroll
      for (int j=0;j<4;j++)
        #pragma unroll
        for (int r=0;r<4;r++)
          eds[(il*16 + quad*4 + r)*64 + j*16 + colw] = acc[i*4+j][r]*sc;
    }
    #pragma unroll
    for (int rr8=0; rr8<8; rr8++){
      int row = rr8*4 + quad;
      float4 v = *(float4*)&eds[row*64 + colw*4];
      int m = bm*128 + wm*64 + ih*32 + row;
      int n = bn*128 + wn*64 + colw*4;
      *(float4*)&G[(size_t)m*H_DIM + n] = v;
    }
  }
}

// Sequential hv step t: emits hs_{t-1} (f16, fragment-tiled into ring slot),
// then hv_t = (hv>vth?0:0.5hv) + G_t, block max -> hmaxA[t+1].
__global__ __launch_bounds__(256) void hv_step(
    const float* __restrict__ Gs, float* __restrict__ hv,
    _Float16* __restrict__ hs_slot,
    const unsigned* __restrict__ hmax_t, unsigned* __restrict__ hmax_n, int t)
{
  __shared__ float red[256];
  const int tid = threadIdx.x;
  const int gid = blockIdx.x*256 + tid;     // 0..131071 (f4 index)
  const int b = gid >> 10, h0 = (gid & 1023) << 2;
  const float vth = vth_of(*hmax_t);
  float4 h = *(const float4*)(hv + (size_t)gid*4);

  if (t > 0){   // hs_{t-1} = hv_{t-1} > vth(max hv_{t-1})
    const int kc = h0>>5, kg=(h0>>3)&3, e=h0&7, r=b&15, m16l=b>>4;
    f16x4 s;
    s[0]=(h.x>vth)?(_Float16)1:(_Float16)0; s[1]=(h.y>vth)?(_Float16)1:(_Float16)0;
    s[2]=(h.z>vth)?(_Float16)1:(_Float16)0; s[3]=(h.w>vth)?(_Float16)1:(_Float16)0;
    *(f16x4*)(hs_slot + ((size_t)m16l*128 + kc)*512 + kg*128 + r*8 + e) = s;
  }
  if (t < T_STEPS){
    float4 g = *(const float4*)(Gs + (size_t)gid*4);
    float4 o;
    o.x = (h.x>vth ? 0.f : 0.5f*h.x) + g.x;
    o.y = (h.y>vth ? 0.f : 0.5f*h.y) + g.y;
    o.z = (h.z>vth ? 0.f : 0.5f*h.z) + g.z;
    o.w = (h.w>vth ? 0.f : 0.5f*h.w) + g.w;
    *(float4*)(hv + (size_t)gid*4) = o;
    red[tid] = fmaxf(fmaxf(o.x,o.y),fmaxf(o.z,o.w));
    __syncthreads();
    for (int s2=128;s2>0;s2>>=1){ if (tid<s2) red[tid]=fmaxf(red[tid],red[tid+s2]); __syncthreads(); }
    if (tid==0) atomicMax(hmax_n, fmap(red[0]));
  }
}

// Batched GEMM2 for one chunk: OG[s] = HS[s] @ Wo^T (A exact f16, B hi/lo).
// grid (4, 20): bn over O/128, bm = t_local. No LDS in main loop (direct
// fragment loads, L2-resident); LDS-staged coalesced epilogue.
__global__ __launch_bounds__(256) void gemm2_mfma(
    const _Float16* __restrict__ HS,
    const _Float16* __restrict__ WoHi, const _Float16* __restrict__ WoLo,
    float* __restrict__ OG, int c)
{
  __shared__ float eds[4][2048];
  const int tid = threadIdx.x, wave = tid>>6, lane = tid&63;
  const int bn = blockIdx.x, bm = blockIdx.y;
  const int s = c*T_CHUNK + bm, ring = s % HS_RING;
  const int wm = wave>>1, wn = wave&1;

  const _Float16* Ab  = HS + ((size_t)(ring*8 + wm*4)*128)*512 + lane*8;
  const _Float16* Bhb = WoHi + ((size_t)(bn*8 + wn*4)*128)*512 + lane*8;
  const _Float16* Blb = WoLo + ((size_t)(bn*8 + wn*4)*128)*512 + lane*8;

  f32x4 acc[16];
  #pragma unroll
  for (int i=0;i<16;i++) acc[i] = (f32x4){0.f,0.f,0.f,0.f};

  int4 ra[4], rh[4], rl[4];
  #pragma unroll
  for (int q=0;q<4;q++){
    ra[q] = *(const int4*)(Ab  + (size_t)q*128*512);
    rh[q] = *(const int4*)(Bhb + (size_t)q*128*512);
    rl[q] = *(const int4*)(Blb + (size_t)q*128*512);
  }
  for (int kc=0;kc<128;kc++){
    f16x8 fA[4], fH[4], fL[4];
    #pragma unroll
    for (int q=0;q<4;q++){
      fA[q] = *(f16x8*)&ra[q]; fH[q] = *(f16x8*)&rh[q]; fL[q] = *(f16x8*)&rl[q];
    }
    if (kc < 127){
      #pragma unroll
      for (int q=0;q<4;q++){
        ra[q] = *(const int4*)(Ab  + ((size_t)q*128 + kc+1)*512);
        rh[q] = *(const int4*)(Bhb + ((size_t)q*128 + kc+1)*512);
        rl[q] = *(const int4*)(Blb + ((size_t)q*128 + kc+1)*512);
      }
    }
    #pragma unroll
    for (int i=0;i<4;i++)
      #pragma unroll
      for (int j=0;j<4;j++)
        acc[i*4+j] = __builtin_amdgcn_mfma_f32_16x16x32_f16(fA[i], fH[j], acc[i*4+j], 0,0,0);
    #pragma unroll
    for (int i=0;i<4;i++)
      #pragma unroll
      for (int j=0;j<4;j++)
        acc[i*4+j] = __builtin_amdgcn_mfma_f32_16x16x32_f16(fA[i], fL[j], acc[i*4+j], 0,0,0);
  }
  const int colw = lane&15, quad = lane>>4;
  const float sc = 1.f/256.f;
  #pragma unroll
  for (int ih=0; ih<2; ih++){
    #pragma unroll
    for (int il=0; il<2; il++){
      int i = ih*2+il;
      #pragma unroll
      for (int j=0;j<4;j++)
        #pragma unroll
        for (int r=0;r<4;r++)
          eds[wave][(il*16 + quad*4 + r)*64 + j*16 + colw] = acc[i*4+j][r]*sc;
    }
    #pragma unroll
    for (int rr8=0; rr8<8; rr8++){
      int row = rr8*4 + quad;
      float4 v = *(float4*)&eds[wave][row*64 + colw*4];
      int m = s*128 + wm*64 + ih*32 + row;
      int n = bn*128 + wn*64 + colw*4;
      *(float4*)&OG[(size_t)m*O_DIM + n] = v;
    }
  }
}

// Whole ov recurrence in ONE block: ov/out state in registers, per-step
// block-internal max reduction — zero global sync, zero barriers.
__global__ __launch_bounds__(1024) void ov_chain(const float* __restrict__ OG,
                                                 float* __restrict__ out)
{
  __shared__ float red[2][16];
  __shared__ float svth;
  const int tid = threadIdx.x, lane = tid&63, wv = tid>>6;
  float ov[64];
  unsigned cnt[16];
  #pragma unroll
  for (int e=0;e<64;e++) ov[e]=0.f;
  #pragma unroll
  for (int q=0;q<16;q++) cnt[q]=0u;

  for (int t=0;t<T_STEPS;t++){
    const float* base = OG + (size_t)t*(B_DIM*O_DIM);
    float lmax = -3.0e38f;
    #pragma unroll
    for (int q=0;q<16;q++){
      float4 og = *(const float4*)(base + ((size_t)q*1024 + tid)*4);
      ov[q*4+0] += og.x; ov[q*4+1] += og.y; ov[q*4+2] += og.z; ov[q*4+3] += og.w;
      lmax = fmaxf(lmax, fmaxf(fmaxf(ov[q*4+0],ov[q*4+1]),fmaxf(ov[q*4+2],ov[q*4+3])));
    }
    #pragma unroll
    for (int off=32; off>0; off>>=1) lmax = fmaxf(lmax, __shfl_down(lmax, off));
    if (lane==0) red[t&1][wv] = lmax;
    __syncthreads();
    if (tid==0){
      float m = red[t&1][0];
      #pragma unroll
      for (int w=1;w<16;w++) m = fmaxf(m, red[t&1][w]);
      svth = 0.3f * tanhf(0.3f * m);
    }
    __syncthreads();
    const float vt = svth;
    #pragma unroll
    for (int q=0;q<16;q++)
      #pragma unroll
      for (int cpt=0;cpt<4;cpt++){
        int e = q*4+cpt;
        bool os = ov[e] > vt;
        cnt[q] += os ? (1u<<(cpt*8)) : 0u;
        ov[e] = os ? 0.f : 0.5f*ov[e];
      }
  }
  #pragma unroll
  for (int q=0;q<16;q++){
    float4 o;
    o.x = (float)( cnt[q]        & 0xffu);
    o.y = (float)((cnt[q] >> 8)  & 0xffu);
    o.z = (float)((cnt[q] >> 16) & 0xffu);
    o.w = (float)((cnt[q] >> 24) & 0xffu);
    *(float4*)(out + ((size_t)q*1024 + tid)*4) = o;
  }
}

extern "C" void kernel_launch(void* const* d_in, const int* in_sizes, int n_in,
                              void* d_out, int out_size, void* d_ws, size_t ws_size,
                              hipStream_t stream) {
  const float* spike = (const float*)d_in[0];
  const float* Wh    = (const float*)d_in[5];   // [H, I]
  const float* Wo    = (const float*)d_in[6];   // [O, H]
  float* out = (float*)d_out;

  char* ws = (char*)d_ws;
  size_t off = 0;
  _Float16* XAhi = (_Float16*)(ws+off); off += (size_t)T_CHUNK*B_DIM*I_DIM*2;
  _Float16* XAlo = (_Float16*)(ws+off); off += (size_t)T_CHUNK*B_DIM*I_DIM*2;
  _Float16* WHhi = (_Float16*)(ws+off); off += (size_t)H_DIM*I_DIM*2;
  _Float16* WHlo = (_Float16*)(ws+off); off += (size_t)H_DIM*I_DIM*2;
  _Float16* WOhi = (_Float16*)(ws+off); off += (size_t)O_DIM*H_DIM*2;
  _Float16* WOlo = (_Float16*)(ws+off); off += (size_t)O_DIM*H_DIM*2;
  float* G  = (float*)(ws+off);         off += (size_t)T_CHUNK*B_DIM*H_DIM*4;
  float* hv = (float*)(ws+off);         off += (size_t)B_DIM*H_DIM*4;
  _Float16* HS = (_Float16*)(ws+off);   off += (size_t)HS_RING*HS_SLOT*2;
  float* OG = (float*)(ws+off);         off += (size_t)T_STEPS*B_DIM*O_DIM*4;
  unsigned* hmaxA = (unsigned*)(ws+off); off += 128*4;
  (void)ws_size; (void)in_sizes; (void)n_in; (void)out_size;

  init_kernel<<<(B_DIM*H_DIM+255)/256, 256, 0, stream>>>(hv, hmaxA);
  prep_w<<<256, 256, 0, stream>>>(Wh, WHhi, WHlo);
  prep_wo<<<32, 256, 0, stream>>>(Wo, WOhi, WOlo);

  for (int c = 0; c < T_STEPS/T_CHUNK; c++){
    prep_x<<<dim3(8,32,2), 256, 0, stream>>>(spike, XAhi, XAlo, c*T_CHUNK);
    gemm1_mfma<<<dim3(32, T_CHUNK), 256, 0, stream>>>(XAhi, XAlo, WHhi, WHlo, G);
    for (int j = 0; j < T_CHUNK; j++){
      int t = c*T_CHUNK + j;
      int ring = (t == 0) ? (HS_RING-1) : ((t-1) % HS_RING);
      hv_step<<<512, 256, 0, stream>>>(
          G + (size_t)j*B_DIM*H_DIM, hv, HS + (size_t)ring*HS_SLOT,
          hmaxA + t, hmaxA + t + 1, t);
      if (j == 0 && c > 0)
        gemm2_mfma<<<dim3(4, T_CHUNK), 256, 0, stream>>>(HS, WOhi, WOlo, OG, c-1);
    }
  }
  // hs_99 tail (t=100: emit-only), then last gemm2 chunk, then the ov chain.
  hv_step<<<512, 256, 0, stream>>>(
      G, hv, HS + (size_t)((T_STEPS-1) % HS_RING)*HS_SLOT,
      hmaxA + T_STEPS, hmaxA + T_STEPS, T_STEPS);
  gemm2_mfma<<<dim3(4, T_CHUNK), 256, 0, stream>>>(HS, WOhi, WOlo, OG, T_STEPS/T_CHUNK - 1);
  ov_chain<<<1, 1024, 0, stream>>>(OG, out);
}

// Round 6
// 3053.252 us; speedup vs baseline: 2.5289x; 1.1553x over previous
//
#include <hip/hip_runtime.h>
#include <math.h>

#define T_STEPS 100
#define B_DIM 128
#define I_DIM 1024
#define H_DIM 4096
#define O_DIM 512
#define T_CHUNK 20
#define HS_RING 21
#define HS_SLOT ((size_t)8*128*512)   // f16 per t-slot (8 m16-tiles x 128 kc x 512)

typedef _Float16 f16x8 __attribute__((ext_vector_type(8)));
typedef _Float16 f16x4 __attribute__((ext_vector_type(4)));
typedef float    f32x4 __attribute__((ext_vector_type(4)));

__device__ __forceinline__ unsigned fmap(float f){
  unsigned u = __float_as_uint(f);
  return (u & 0x80000000u) ? ~u : (u | 0x80000000u);
}
__device__ __forceinline__ float funmap(unsigned m){
  unsigned u = (m & 0x80000000u) ? (m & 0x7FFFFFFFu) : ~m;
  return __uint_as_float(u);
}
__device__ __forceinline__ float vth_of(unsigned m){
  return 0.3f * tanhf(0.3f * funmap(m));
}

__global__ __launch_bounds__(256) void init_kernel(float* hv, unsigned* hmaxA)
{
  int i = blockIdx.x * 256 + threadIdx.x;
  if (i < B_DIM*H_DIM) hv[i] = 0.f;
  if (i < 128) hmaxA[i] = (i==0) ? 0x80000000u : fmap(-3.0e38f); // slot0 = max(0)
}

// spike_data [B][I][T] fp32 -> fragment-tiled f16 hi/lo of (x*2048), chunk of 20 t.
__global__ __launch_bounds__(256) void prep_x(const float* __restrict__ sp,
                                              _Float16* __restrict__ Ahi,
                                              _Float16* __restrict__ Alo, int t0)
{
  __shared__ float tile[32][16][10];
  const int b16 = blockIdx.x, kc = blockIdx.y, tz = blockIdx.z;
  for (int e = threadIdx.x; e < 5120; e += 256){
    int tt = e % 10, row = e / 10;
    int bb = row >> 5, ii = row & 31;
    tile[ii][bb][tt] =
      sp[((size_t)(b16*16+bb)*I_DIM + kc*32 + ii)*T_STEPS + t0 + tz*10 + tt];
  }
  __syncthreads();
  for (int u = threadIdx.x; u < 640; u += 256){
    int tl = u >> 6, l = u & 63, kg = l >> 4, r = l & 15;
    f16x8 hi, lo;
    #pragma unroll
    for (int e=0;e<8;e++){
      float x = tile[kg*8+e][r][tl] * 2048.f;
      _Float16 h = (_Float16)x;
      hi[e] = h;
      lo[e] = (_Float16)(x - (float)h);
    }
    int t_local = tz*10 + tl;
    size_t off = ((size_t)(t_local*8 + b16)*32 + kc)*512 + kg*128 + r*8;
    *(f16x8*)(Ahi + off) = hi;
    *(f16x8*)(Alo + off) = lo;
  }
}

// Wh [H][I] fp32 -> FB-tiled f16 hi/lo of (w*256).
__global__ __launch_bounds__(256) void prep_w(const float* __restrict__ Wh,
                                              _Float16* __restrict__ Bhi,
                                              _Float16* __restrict__ Blo)
{
  const int n16 = blockIdx.x;
  for (int u = threadIdx.x; u < 2048; u += 256){
    int kc = u >> 6, l = u & 63, kg = l >> 4, r = l & 15;
    const float* src = Wh + (size_t)(n16*16 + r)*I_DIM + kc*32 + kg*8;
    f16x8 hi, lo;
    #pragma unroll
    for (int e=0;e<8;e++){
      float x = src[e] * 256.f;
      _Float16 h = (_Float16)x;
      hi[e] = h;
      lo[e] = (_Float16)(x - (float)h);
    }
    size_t off = ((size_t)n16*32 + kc)*512 + kg*128 + r*8;
    *(f16x8*)(Bhi + off) = hi;
    *(f16x8*)(Blo + off) = lo;
  }
}

// Wo [O][H] fp32 -> FB-tiled f16 hi/lo of (w*256). 128 kc over H.
__global__ __launch_bounds__(256) void prep_wo(const float* __restrict__ Wo,
                                               _Float16* __restrict__ Bhi,
                                               _Float16* __restrict__ Blo)
{
  const int n16 = blockIdx.x;   // 0..31
  for (int u = threadIdx.x; u < 8192; u += 256){
    int kc = u >> 6, l = u & 63, kg = l >> 4, r = l & 15;
    const float* src = Wo + (size_t)(n16*16 + r)*H_DIM + kc*32 + kg*8;
    f16x8 hi, lo;
    #pragma unroll
    for (int e=0;e<8;e++){
      float x = src[e] * 256.f;
      _Float16 h = (_Float16)x;
      hi[e] = h;
      lo[e] = (_Float16)(x - (float)h);
    }
    size_t off = ((size_t)(n16*128 + kc))*512 + kg*128 + r*8;
    *(f16x8*)(Bhi + off) = hi;
    *(f16x8*)(Blo + off) = lo;
  }
}

// Batched GEMM1 (chunk of 20 t): G = XT @ Wh^T via fp16x3 exact-split MFMA.
__global__ __launch_bounds__(256) void gemm1_mfma(
    const _Float16* __restrict__ Ahi, const _Float16* __restrict__ Alo,
    const _Float16* __restrict__ Bhi, const _Float16* __restrict__ Blo,
    float* __restrict__ G)
{
  __shared__ __align__(16) _Float16 lds[4][8][512];
  const int tid = threadIdx.x, wave = tid>>6, lane = tid&63;
  const int bn = blockIdx.x, bm = blockIdx.y;
  const int m16b = bm*8, n16b = bn*8;
  const int wm = wave>>1, wn = wave&1;

  const _Float16* srcbase = (wave==0)?Ahi:(wave==1)?Alo:(wave==2)?Bhi:Blo;
  const int r16b = (wave<2) ? m16b : n16b;

  f32x4 acc[16];
  #pragma unroll
  for (int i=0;i<16;i++) acc[i] = (f32x4){0.f,0.f,0.f,0.f};

  int4 rr[8];
  #pragma unroll
  for (int q=0;q<8;q++)
    rr[q] = *(const int4*)(srcbase + ((size_t)(r16b+q)*32)*512 + lane*8);

  for (int kc=0;kc<32;kc++){
    __syncthreads();
    #pragma unroll
    for (int q=0;q<8;q++) *(int4*)&lds[wave][q][lane*8] = rr[q];
    __syncthreads();
    if (kc < 31){
      #pragma unroll
      for (int q=0;q<8;q++)
        rr[q] = *(const int4*)(srcbase + ((size_t)(r16b+q)*32 + kc+1)*512 + lane*8);
    }
    f16x8 fAh[4], fAl[4], fBh[4], fBl[4];
    #pragma unroll
    for (int i=0;i<4;i++){
      fAh[i] = *(const f16x8*)&lds[0][wm*4+i][lane*8];
      fAl[i] = *(const f16x8*)&lds[1][wm*4+i][lane*8];
      fBh[i] = *(const f16x8*)&lds[2][wn*4+i][lane*8];
      fBl[i] = *(const f16x8*)&lds[3][wn*4+i][lane*8];
    }
    #pragma unroll
    for (int i=0;i<4;i++)
      #pragma unroll
      for (int j=0;j<4;j++)
        acc[i*4+j] = __builtin_amdgcn_mfma_f32_16x16x32_f16(fAh[i], fBh[j], acc[i*4+j], 0,0,0);
    #pragma unroll
    for (int i=0;i<4;i++)
      #pragma unroll
      for (int j=0;j<4;j++)
        acc[i*4+j] = __builtin_amdgcn_mfma_f32_16x16x32_f16(fAh[i], fBl[j], acc[i*4+j], 0,0,0);
    #pragma unroll
    for (int i=0;i<4;i++)
      #pragma unroll
      for (int j=0;j<4;j++)
        acc[i*4+j] = __builtin_amdgcn_mfma_f32_16x16x32_f16(fAl[i], fBh[j], acc[i*4+j], 0,0,0);
  }
  const int colw = lane&15, quad = lane>>4;
  const float sc = 1.f/(2048.f*256.f);
  float* eds = (float*)lds + wave*2048;
  __syncthreads();
  #pragma unroll
  for (int ih=0; ih<2; ih++){
    #pragma unroll
    for (int il=0; il<2; il++){
      int i = ih*2+il;
      #pragma unroll
      for (int j=0;j<4;j++)
        #pragma unroll
        for (int r=0;r<4;r++)
          eds[(il*16 + quad*4 + r)*64 + j*16 + colw] = acc[i*4+j][r]*sc;
    }
    #pragma unroll
    for (int rr8=0; rr8<8; rr8++){
      int row = rr8*4 + quad;
      float4 v = *(float4*)&eds[row*64 + colw*4];
      int m = bm*128 + wm*64 + ih*32 + row;
      int n = bn*128 + wn*64 + colw*4;
      *(float4*)&G[(size_t)m*H_DIM + n] = v;
    }
  }
}

// Sequential hv step t: emits hs_{t-1} (f16, fragment-tiled into ring slot),
// then hv_t = (hv>vth?0:0.5hv) + G_t, block max -> hmaxA[t+1].
__global__ __launch_bounds__(256) void hv_step(
    const float* __restrict__ Gs, float* __restrict__ hv,
    _Float16* __restrict__ hs_slot,
    const unsigned* __restrict__ hmax_t, unsigned* __restrict__ hmax_n, int t)
{
  __shared__ float red[256];
  const int tid = threadIdx.x;
  const int gid = blockIdx.x*256 + tid;     // 0..131071 (f4 index)
  const int b = gid >> 10, h0 = (gid & 1023) << 2;
  const float vth = vth_of(*hmax_t);
  float4 h = *(const float4*)(hv + (size_t)gid*4);

  if (t > 0){   // hs_{t-1} = hv_{t-1} > vth(max hv_{t-1})
    const int kc = h0>>5, kg=(h0>>3)&3, e=h0&7, r=b&15, m16l=b>>4;
    f16x4 s;
    s[0]=(h.x>vth)?(_Float16)1:(_Float16)0; s[1]=(h.y>vth)?(_Float16)1:(_Float16)0;
    s[2]=(h.z>vth)?(_Float16)1:(_Float16)0; s[3]=(h.w>vth)?(_Float16)1:(_Float16)0;
    *(f16x4*)(hs_slot + ((size_t)m16l*128 + kc)*512 + kg*128 + r*8 + e) = s;
  }
  if (t < T_STEPS){
    float4 g = *(const float4*)(Gs + (size_t)gid*4);
    float4 o;
    o.x = (h.x>vth ? 0.f : 0.5f*h.x) + g.x;
    o.y = (h.y>vth ? 0.f : 0.5f*h.y) + g.y;
    o.z = (h.z>vth ? 0.f : 0.5f*h.z) + g.z;
    o.w = (h.w>vth ? 0.f : 0.5f*h.w) + g.w;
    *(float4*)(hv + (size_t)gid*4) = o;
    red[tid] = fmaxf(fmaxf(o.x,o.y),fmaxf(o.z,o.w));
    __syncthreads();
    for (int s2=128;s2>0;s2>>=1){ if (tid<s2) red[tid]=fmaxf(red[tid],red[tid+s2]); __syncthreads(); }
    if (tid==0) atomicMax(hmax_n, fmap(red[0]));
  }
}

// Batched GEMM2 for one chunk: OG[s] = HS[s] @ Wo^T (A exact f16, B hi/lo).
__global__ __launch_bounds__(256) void gemm2_mfma(
    const _Float16* __restrict__ HS,
    const _Float16* __restrict__ WoHi, const _Float16* __restrict__ WoLo,
    float* __restrict__ OG, int c)
{
  __shared__ float eds[4][2048];
  const int tid = threadIdx.x, wave = tid>>6, lane = tid&63;
  const int bn = blockIdx.x, bm = blockIdx.y;
  const int s = c*T_CHUNK + bm, ring = s % HS_RING;
  const int wm = wave>>1, wn = wave&1;

  const _Float16* Ab  = HS + ((size_t)(ring*8 + wm*4)*128)*512 + lane*8;
  const _Float16* Bhb = WoHi + ((size_t)(bn*8 + wn*4)*128)*512 + lane*8;
  const _Float16* Blb = WoLo + ((size_t)(bn*8 + wn*4)*128)*512 + lane*8;

  f32x4 acc[16];
  #pragma unroll
  for (int i=0;i<16;i++) acc[i] = (f32x4){0.f,0.f,0.f,0.f};

  int4 ra[4], rh[4], rl[4];
  #pragma unroll
  for (int q=0;q<4;q++){
    ra[q] = *(const int4*)(Ab  + (size_t)q*128*512);
    rh[q] = *(const int4*)(Bhb + (size_t)q*128*512);
    rl[q] = *(const int4*)(Blb + (size_t)q*128*512);
  }
  for (int kc=0;kc<128;kc++){
    f16x8 fA[4], fH[4], fL[4];
    #pragma unroll
    for (int q=0;q<4;q++){
      fA[q] = *(f16x8*)&ra[q]; fH[q] = *(f16x8*)&rh[q]; fL[q] = *(f16x8*)&rl[q];
    }
    if (kc < 127){
      #pragma unroll
      for (int q=0;q<4;q++){
        ra[q] = *(const int4*)(Ab  + ((size_t)q*128 + kc+1)*512);
        rh[q] = *(const int4*)(Bhb + ((size_t)q*128 + kc+1)*512);
        rl[q] = *(const int4*)(Blb + ((size_t)q*128 + kc+1)*512);
      }
    }
    #pragma unroll
    for (int i=0;i<4;i++)
      #pragma unroll
      for (int j=0;j<4;j++)
        acc[i*4+j] = __builtin_amdgcn_mfma_f32_16x16x32_f16(fA[i], fH[j], acc[i*4+j], 0,0,0);
    #pragma unroll
    for (int i=0;i<4;i++)
      #pragma unroll
      for (int j=0;j<4;j++)
        acc[i*4+j] = __builtin_amdgcn_mfma_f32_16x16x32_f16(fA[i], fL[j], acc[i*4+j], 0,0,0);
  }
  const int colw = lane&15, quad = lane>>4;
  const float sc = 1.f/256.f;
  #pragma unroll
  for (int ih=0; ih<2; ih++){
    #pragma unroll
    for (int il=0; il<2; il++){
      int i = ih*2+il;
      #pragma unroll
      for (int j=0;j<4;j++)
        #pragma unroll
        for (int r=0;r<4;r++)
          eds[wave][(il*16 + quad*4 + r)*64 + j*16 + colw] = acc[i*4+j][r]*sc;
    }
    #pragma unroll
    for (int rr8=0; rr8<8; rr8++){
      int row = rr8*4 + quad;
      float4 v = *(float4*)&eds[wave][row*64 + colw*4];
      int m = s*128 + wm*64 + ih*32 + row;
      int n = bn*128 + wn*64 + colw*4;
      *(float4*)&OG[(size_t)m*O_DIM + n] = v;
    }
  }
}

// Whole ov recurrence in ONE block, software-pipelined:
// quarter-slice double-buffer prefetch (issue-before-consume) so the 256KB/step
// OG read flies during VALU + reduction; per-step spikes emitted as 64-bit
// masks (8B/thread) — counts materialized by count_kernel afterwards.
__global__ __launch_bounds__(1024) void ov_chain(const float* __restrict__ OG,
                                                 unsigned* __restrict__ bits)
{
  __shared__ float red[16];
  __shared__ float svth;
  const int tid = threadIdx.x, lane = tid&63, wv = tid>>6;
  float ov[64];
  #pragma unroll
  for (int e=0;e<64;e++) ov[e]=0.f;

  const float* base = OG + tid*4;      // slice layout: float4 idx = q*1024+tid
  float4 P[2][4];
  #pragma unroll
  for (int p=0;p<4;p++) P[0][p] = *(const float4*)(base + p*4096);  // Q0 of t=0

  for (int t=0;t<T_STEPS;t++){
    const float* cur = base + (size_t)t*65536;
    float lmax = -3.0e38f;
    #pragma unroll
    for (int qq=0; qq<4; qq++){
      // issue next quarter BEFORE consuming current (alternating buffers)
      if (qq < 3){
        #pragma unroll
        for (int p=0;p<4;p++)
          P[(qq+1)&1][p] = *(const float4*)(cur + ((qq+1)*4+p)*4096);
      } else if (t+1 < T_STEPS){
        #pragma unroll
        for (int p=0;p<4;p++)
          P[0][p] = *(const float4*)(cur + 65536 + p*4096);   // Q0 of t+1
      }
      const float4* Pc = P[qq&1];
      #pragma unroll
      for (int p=0;p<4;p++){
        int e = qq*16 + p*4;
        ov[e+0] += Pc[p].x; ov[e+1] += Pc[p].y;
        ov[e+2] += Pc[p].z; ov[e+3] += Pc[p].w;
        lmax = fmaxf(lmax, fmaxf(fmaxf(ov[e+0],ov[e+1]),fmaxf(ov[e+2],ov[e+3])));
      }
    }
    #pragma unroll
    for (int off=32; off>0; off>>=1) lmax = fmaxf(lmax, __shfl_down(lmax, off));
    if (lane==0) red[wv] = lmax;
    __syncthreads();
    if (tid==0){
      float m = red[0];
      #pragma unroll
      for (int w=1;w<16;w++) m = fmaxf(m, red[w]);
      svth = 0.3f * tanhf(0.3f * m);
    }
    __syncthreads();
    const float vt = svth;
    unsigned b0=0u, b1=0u;
    #pragma unroll
    for (int e=0;e<32;e++){
      bool os = ov[e] > vt;
      b0 |= os ? (1u<<e) : 0u;
      ov[e] = os ? 0.f : 0.5f*ov[e];
    }
    #pragma unroll
    for (int e=32;e<64;e++){
      bool os = ov[e] > vt;
      b1 |= os ? (1u<<(e-32)) : 0u;
      ov[e] = os ? 0.f : 0.5f*ov[e];
    }
    uint2 bv; bv.x=b0; bv.y=b1;
    *(uint2*)(bits + ((size_t)t*1024 + tid)*2) = bv;
  }
}

// out[o] = sum over t of spike bit for element o.
__global__ __launch_bounds__(256) void count_kernel(const unsigned* __restrict__ bits,
                                                    float* __restrict__ out)
{
  const int o = blockIdx.x*256 + threadIdx.x;   // 0..65535
  const int f4 = o>>2, c = o&3;
  const int q = f4>>10, tid = f4&1023;
  const int qq = q>>2, p = q&3;
  const int b = qq*16 + p*4 + c, w = b>>5, pos = b&31;
  const unsigned* src = bits + tid*2 + w;
  unsigned cnt=0;
  #pragma unroll 4
  for (int t=0;t<T_STEPS;t++) cnt += (src[(size_t)t*2048] >> pos) & 1u;
  out[o] = (float)cnt;
}

extern "C" void kernel_launch(void* const* d_in, const int* in_sizes, int n_in,
                              void* d_out, int out_size, void* d_ws, size_t ws_size,
                              hipStream_t stream) {
  const float* spike = (const float*)d_in[0];
  const float* Wh    = (const float*)d_in[5];   // [H, I]
  const float* Wo    = (const float*)d_in[6];   // [O, H]
  float* out = (float*)d_out;

  char* ws = (char*)d_ws;
  size_t off = 0;
  _Float16* XAhi = (_Float16*)(ws+off); off += (size_t)T_CHUNK*B_DIM*I_DIM*2;
  _Float16* XAlo = (_Float16*)(ws+off); off += (size_t)T_CHUNK*B_DIM*I_DIM*2;
  _Float16* WHhi = (_Float16*)(ws+off); off += (size_t)H_DIM*I_DIM*2;
  _Float16* WHlo = (_Float16*)(ws+off); off += (size_t)H_DIM*I_DIM*2;
  _Float16* WOhi = (_Float16*)(ws+off); off += (size_t)O_DIM*H_DIM*2;
  _Float16* WOlo = (_Float16*)(ws+off); off += (size_t)O_DIM*H_DIM*2;
  float* G  = (float*)(ws+off);         off += (size_t)T_CHUNK*B_DIM*H_DIM*4;
  float* hv = (float*)(ws+off);         off += (size_t)B_DIM*H_DIM*4;
  _Float16* HS = (_Float16*)(ws+off);   off += (size_t)HS_RING*HS_SLOT*2;
  float* OG = (float*)(ws+off);         off += (size_t)T_STEPS*B_DIM*O_DIM*4;
  unsigned* bits = (unsigned*)(ws+off); off += (size_t)T_STEPS*1024*2*4;
  unsigned* hmaxA = (unsigned*)(ws+off); off += 128*4;
  (void)ws_size; (void)in_sizes; (void)n_in; (void)out_size;

  init_kernel<<<(B_DIM*H_DIM+255)/256, 256, 0, stream>>>(hv, hmaxA);
  prep_w<<<256, 256, 0, stream>>>(Wh, WHhi, WHlo);
  prep_wo<<<32, 256, 0, stream>>>(Wo, WOhi, WOlo);

  for (int c = 0; c < T_STEPS/T_CHUNK; c++){
    prep_x<<<dim3(8,32,2), 256, 0, stream>>>(spike, XAhi, XAlo, c*T_CHUNK);
    gemm1_mfma<<<dim3(32, T_CHUNK), 256, 0, stream>>>(XAhi, XAlo, WHhi, WHlo, G);
    for (int j = 0; j < T_CHUNK; j++){
      int t = c*T_CHUNK + j;
      int ring = (t == 0) ? (HS_RING-1) : ((t-1) % HS_RING);
      hv_step<<<512, 256, 0, stream>>>(
          G + (size_t)j*B_DIM*H_DIM, hv, HS + (size_t)ring*HS_SLOT,
          hmaxA + t, hmaxA + t + 1, t);
      if (j == 0 && c > 0)
        gemm2_mfma<<<dim3(4, T_CHUNK), 256, 0, stream>>>(HS, WOhi, WOlo, OG, c-1);
    }
  }
  // hs_99 tail (t=100: emit-only), then last gemm2 chunk, then the ov chain.
  hv_step<<<512, 256, 0, stream>>>(
      G, hv, HS + (size_t)((T_STEPS-1) % HS_RING)*HS_SLOT,
      hmaxA + T_STEPS, hmaxA + T_STEPS, T_STEPS);
  gemm2_mfma<<<dim3(4, T_CHUNK), 256, 0, stream>>>(HS, WOhi, WOlo, OG, T_STEPS/T_CHUNK - 1);
  ov_chain<<<1, 1024, 0, stream>>>(OG, bits);
  count_kernel<<<256, 256, 0, stream>>>(bits, out);
}

// Round 7
// 2714.089 us; speedup vs baseline: 2.8449x; 1.1250x over previous
//
#include <hip/hip_runtime.h>
#include <math.h>
#include <stdint.h>

#define T_STEPS 100
#define B_DIM 128
#define I_DIM 1024
#define H_DIM 4096
#define O_DIM 512
#define T_CHUNK 20
#define HS_RING 21
#define HS_SLOT ((size_t)8*128*512)   // f16 per t-slot (8 m16-tiles x 128 kc x 512)

typedef _Float16 f16x8 __attribute__((ext_vector_type(8)));
typedef _Float16 f16x4 __attribute__((ext_vector_type(4)));
typedef float    f32x4 __attribute__((ext_vector_type(4)));

#define AS1 __attribute__((address_space(1)))
#define AS3 __attribute__((address_space(3)))

// Async global->LDS, 16B/lane. LDS dest is wave-uniform base + lane*16 (m104),
// which exactly matches the 1KB fragment-block layout (64 lanes x 16B).
__device__ __forceinline__ void gload_lds16(const _Float16* g, _Float16* l){
  __builtin_amdgcn_global_load_lds(
      (const AS1 unsigned*)(uintptr_t)g,
      (AS3 unsigned*)(unsigned)(uintptr_t)l, 16, 0, 0);
}

__device__ __forceinline__ unsigned fmap(float f){
  unsigned u = __float_as_uint(f);
  return (u & 0x80000000u) ? ~u : (u | 0x80000000u);
}
__device__ __forceinline__ float funmap(unsigned m){
  unsigned u = (m & 0x80000000u) ? (m & 0x7FFFFFFFu) : ~m;
  return __uint_as_float(u);
}
__device__ __forceinline__ float vth_of(unsigned m){
  return 0.3f * tanhf(0.3f * funmap(m));
}

__global__ __launch_bounds__(256) void init_kernel(float* hv, unsigned* hmaxA)
{
  int i = blockIdx.x * 256 + threadIdx.x;
  if (i < B_DIM*H_DIM) hv[i] = 0.f;
  if (i < 128) hmaxA[i] = (i==0) ? 0x80000000u : fmap(-3.0e38f); // slot0 = max(0)
}

// spike_data [B][I][T] fp32 -> fragment-tiled f16 hi/lo of (x*2048), chunk of 20 t.
__global__ __launch_bounds__(256) void prep_x(const float* __restrict__ sp,
                                              _Float16* __restrict__ Ahi,
                                              _Float16* __restrict__ Alo, int t0)
{
  __shared__ float tile[32][16][10];
  const int b16 = blockIdx.x, kc = blockIdx.y, tz = blockIdx.z;
  for (int e = threadIdx.x; e < 5120; e += 256){
    int tt = e % 10, row = e / 10;
    int bb = row >> 5, ii = row & 31;
    tile[ii][bb][tt] =
      sp[((size_t)(b16*16+bb)*I_DIM + kc*32 + ii)*T_STEPS + t0 + tz*10 + tt];
  }
  __syncthreads();
  for (int u = threadIdx.x; u < 640; u += 256){
    int tl = u >> 6, l = u & 63, kg = l >> 4, r = l & 15;
    f16x8 hi, lo;
    #pragma unroll
    for (int e=0;e<8;e++){
      float x = tile[kg*8+e][r][tl] * 2048.f;
      _Float16 h = (_Float16)x;
      hi[e] = h;
      lo[e] = (_Float16)(x - (float)h);
    }
    int t_local = tz*10 + tl;
    size_t off = ((size_t)(t_local*8 + b16)*32 + kc)*512 + kg*128 + r*8;
    *(f16x8*)(Ahi + off) = hi;
    *(f16x8*)(Alo + off) = lo;
  }
}

// Wh [H][I] fp32 -> FB-tiled f16 hi/lo of (w*256).
__global__ __launch_bounds__(256) void prep_w(const float* __restrict__ Wh,
                                              _Float16* __restrict__ Bhi,
                                              _Float16* __restrict__ Blo)
{
  const int n16 = blockIdx.x;
  for (int u = threadIdx.x; u < 2048; u += 256){
    int kc = u >> 6, l = u & 63, kg = l >> 4, r = l & 15;
    const float* src = Wh + (size_t)(n16*16 + r)*I_DIM + kc*32 + kg*8;
    f16x8 hi, lo;
    #pragma unroll
    for (int e=0;e<8;e++){
      float x = src[e] * 256.f;
      _Float16 h = (_Float16)x;
      hi[e] = h;
      lo[e] = (_Float16)(x - (float)h);
    }
    size_t off = ((size_t)n16*32 + kc)*512 + kg*128 + r*8;
    *(f16x8*)(Bhi + off) = hi;
    *(f16x8*)(Blo + off) = lo;
  }
}

// Wo [O][H] fp32 -> FB-tiled f16 hi/lo of (w*256). 128 kc over H.
__global__ __launch_bounds__(256) void prep_wo(const float* __restrict__ Wo,
                                               _Float16* __restrict__ Bhi,
                                               _Float16* __restrict__ Blo)
{
  const int n16 = blockIdx.x;   // 0..31
  for (int u = threadIdx.x; u < 8192; u += 256){
    int kc = u >> 6, l = u & 63, kg = l >> 4, r = l & 15;
    const float* src = Wo + (size_t)(n16*16 + r)*H_DIM + kc*32 + kg*8;
    f16x8 hi, lo;
    #pragma unroll
    for (int e=0;e<8;e++){
      float x = src[e] * 256.f;
      _Float16 h = (_Float16)x;
      hi[e] = h;
      lo[e] = (_Float16)(x - (float)h);
    }
    size_t off = ((size_t)(n16*128 + kc))*512 + kg*128 + r*8;
    *(f16x8*)(Bhi + off) = hi;
    *(f16x8*)(Blo + off) = lo;
  }
}

// Batched GEMM1 (chunk of 20 t): G = XT @ Wh^T via fp16x3 exact-split MFMA.
// K-loop: async global_load_lds double-buffer, ONE barrier per kc (m97 form).
__global__ __launch_bounds__(256, 2) void gemm1_mfma(
    const _Float16* __restrict__ Ahi, const _Float16* __restrict__ Alo,
    const _Float16* __restrict__ Bhi, const _Float16* __restrict__ Blo,
    float* __restrict__ G)
{
  __shared__ __align__(16) _Float16 lds[2][4][8][512];   // 64 KB, 2 blocks/CU
  const int tid = threadIdx.x, wave = tid>>6, lane = tid&63;
  const int bn = blockIdx.x, bm = blockIdx.y;
  const int wm = wave>>1, wn = wave&1;

  const _Float16* srcbase = (wave==0)?Ahi:(wave==1)?Alo:(wave==2)?Bhi:Blo;
  const int r16b = ((wave<2) ? bm : bn)*8;
  const _Float16* gsrc = srcbase + (size_t)r16b*32*512 + lane*8;

  f32x4 acc[16];
  #pragma unroll
  for (int i=0;i<16;i++) acc[i] = (f32x4){0.f,0.f,0.f,0.f};

  // stage kc=0 into buffer 0
  #pragma unroll
  for (int q=0;q<8;q++)
    gload_lds16(gsrc + (size_t)q*32*512, &lds[0][wave][q][0]);

  for (int kc=0;kc<32;kc++){
    __syncthreads();              // vmcnt(0) drain + barrier: buf[kc&1] ready
    if (kc < 31){                 // async prefetch kc+1; flies during compute
      #pragma unroll
      for (int q=0;q<8;q++)
        gload_lds16(gsrc + ((size_t)q*32 + kc+1)*512, &lds[(kc+1)&1][wave][q][0]);
    }
    const int cb = kc&1;
    f16x8 fAh[4], fAl[4], fBh[4], fBl[4];
    #pragma unroll
    for (int i=0;i<4;i++){
      fAh[i] = *(const f16x8*)&lds[cb][0][wm*4+i][lane*8];
      fAl[i] = *(const f16x8*)&lds[cb][1][wm*4+i][lane*8];
      fBh[i] = *(const f16x8*)&lds[cb][2][wn*4+i][lane*8];
      fBl[i] = *(const f16x8*)&lds[cb][3][wn*4+i][lane*8];
    }
    #pragma unroll
    for (int i=0;i<4;i++)
      #pragma unroll
      for (int j=0;j<4;j++)
        acc[i*4+j] = __builtin_amdgcn_mfma_f32_16x16x32_f16(fAh[i], fBh[j], acc[i*4+j], 0,0,0);
    #pragma unroll
    for (int i=0;i<4;i++)
      #pragma unroll
      for (int j=0;j<4;j++)
        acc[i*4+j] = __builtin_amdgcn_mfma_f32_16x16x32_f16(fAh[i], fBl[j], acc[i*4+j], 0,0,0);
    #pragma unroll
    for (int i=0;i<4;i++)
      #pragma unroll
      for (int j=0;j<4;j++)
        acc[i*4+j] = __builtin_amdgcn_mfma_f32_16x16x32_f16(fAl[i], fBh[j], acc[i*4+j], 0,0,0);
  }
  const int colw = lane&15, quad = lane>>4;
  const float sc = 1.f/(2048.f*256.f);
  float* eds = (float*)lds + wave*2048;
  __syncthreads();
  #pragma unroll
  for (int ih=0; ih<2; ih++){
    #pragma unroll
    for (int il=0; il<2; il++){
      int i = ih*2+il;
      #pragma unroll
      for (int j=0;j<4;j++)
        #pragma unroll
        for (int r=0;r<4;r++)
          eds[(il*16 + quad*4 + r)*64 + j*16 + colw] = acc[i*4+j][r]*sc;
    }
    #pragma unroll
    for (int rr8=0; rr8<8; rr8++){
      int row = rr8*4 + quad;
      float4 v = *(float4*)&eds[row*64 + colw*4];
      int m = bm*128 + wm*64 + ih*32 + row;
      int n = bn*128 + wn*64 + colw*4;
      *(float4*)&G[(size_t)m*H_DIM + n] = v;
    }
  }
}

// Sequential hv step t: emits hs_{t-1} (f16, fragment-tiled into ring slot),
// then hv_t = (hv>vth?0:0.5hv) + G_t, block max -> hmaxA[t+1].
__global__ __launch_bounds__(256) void hv_step(
    const float* __restrict__ Gs, float* __restrict__ hv,
    _Float16* __restrict__ hs_slot,
    const unsigned* __restrict__ hmax_t, unsigned* __restrict__ hmax_n, int t)
{
  __shared__ float red[256];
  const int tid = threadIdx.x;
  const int gid = blockIdx.x*256 + tid;     // 0..131071 (f4 index)
  const int b = gid >> 10, h0 = (gid & 1023) << 2;
  const float vth = vth_of(*hmax_t);
  float4 h = *(const float4*)(hv + (size_t)gid*4);

  if (t > 0){   // hs_{t-1} = hv_{t-1} > vth(max hv_{t-1})
    const int kc = h0>>5, kg=(h0>>3)&3, e=h0&7, r=b&15, m16l=b>>4;
    f16x4 s;
    s[0]=(h.x>vth)?(_Float16)1:(_Float16)0; s[1]=(h.y>vth)?(_Float16)1:(_Float16)0;
    s[2]=(h.z>vth)?(_Float16)1:(_Float16)0; s[3]=(h.w>vth)?(_Float16)1:(_Float16)0;
    *(f16x4*)(hs_slot + ((size_t)m16l*128 + kc)*512 + kg*128 + r*8 + e) = s;
  }
  if (t < T_STEPS){
    float4 g = *(const float4*)(Gs + (size_t)gid*4);
    float4 o;
    o.x = (h.x>vth ? 0.f : 0.5f*h.x) + g.x;
    o.y = (h.y>vth ? 0.f : 0.5f*h.y) + g.y;
    o.z = (h.z>vth ? 0.f : 0.5f*h.z) + g.z;
    o.w = (h.w>vth ? 0.f : 0.5f*h.w) + g.w;
    *(float4*)(hv + (size_t)gid*4) = o;
    red[tid] = fmaxf(fmaxf(o.x,o.y),fmaxf(o.z,o.w));
    __syncthreads();
    for (int s2=128;s2>0;s2>>=1){ if (tid<s2) red[tid]=fmaxf(red[tid],red[tid+s2]); __syncthreads(); }
    if (tid==0) atomicMax(hmax_n, fmap(red[0]));
  }
}

// Batched GEMM2 for one chunk: OG[s] = HS[s] @ Wo^T (A exact f16, B hi/lo).
__global__ __launch_bounds__(256) void gemm2_mfma(
    const _Float16* __restrict__ HS,
    const _Float16* __restrict__ WoHi, const _Float16* __restrict__ WoLo,
    float* __restrict__ OG, int c)
{
  __shared__ float eds[4][2048];
  const int tid = threadIdx.x, wave = tid>>6, lane = tid&63;
  const int bn = blockIdx.x, bm = blockIdx.y;
  const int s = c*T_CHUNK + bm, ring = s % HS_RING;
  const int wm = wave>>1, wn = wave&1;

  const _Float16* Ab  = HS + ((size_t)(ring*8 + wm*4)*128)*512 + lane*8;
  const _Float16* Bhb = WoHi + ((size_t)(bn*8 + wn*4)*128)*512 + lane*8;
  const _Float16* Blb = WoLo + ((size_t)(bn*8 + wn*4)*128)*512 + lane*8;

  f32x4 acc[16];
  #pragma unroll
  for (int i=0;i<16;i++) acc[i] = (f32x4){0.f,0.f,0.f,0.f};

  int4 ra[4], rh[4], rl[4];
  #pragma unroll
  for (int q=0;q<4;q++){
    ra[q] = *(const int4*)(Ab  + (size_t)q*128*512);
    rh[q] = *(const int4*)(Bhb + (size_t)q*128*512);
    rl[q] = *(const int4*)(Blb + (size_t)q*128*512);
  }
  for (int kc=0;kc<128;kc++){
    f16x8 fA[4], fH[4], fL[4];
    #pragma unroll
    for (int q=0;q<4;q++){
      fA[q] = *(f16x8*)&ra[q]; fH[q] = *(f16x8*)&rh[q]; fL[q] = *(f16x8*)&rl[q];
    }
    if (kc < 127){
      #pragma unroll
      for (int q=0;q<4;q++){
        ra[q] = *(const int4*)(Ab  + ((size_t)q*128 + kc+1)*512);
        rh[q] = *(const int4*)(Bhb + ((size_t)q*128 + kc+1)*512);
        rl[q] = *(const int4*)(Blb + ((size_t)q*128 + kc+1)*512);
      }
    }
    #pragma unroll
    for (int i=0;i<4;i++)
      #pragma unroll
      for (int j=0;j<4;j++)
        acc[i*4+j] = __builtin_amdgcn_mfma_f32_16x16x32_f16(fA[i], fH[j], acc[i*4+j], 0,0,0);
    #pragma unroll
    for (int i=0;i<4;i++)
      #pragma unroll
      for (int j=0;j<4;j++)
        acc[i*4+j] = __builtin_amdgcn_mfma_f32_16x16x32_f16(fA[i], fL[j], acc[i*4+j], 0,0,0);
  }
  const int colw = lane&15, quad = lane>>4;
  const float sc = 1.f/256.f;
  #pragma unroll
  for (int ih=0; ih<2; ih++){
    #pragma unroll
    for (int il=0; il<2; il++){
      int i = ih*2+il;
      #pragma unroll
      for (int j=0;j<4;j++)
        #pragma unroll
        for (int r=0;r<4;r++)
          eds[wave][(il*16 + quad*4 + r)*64 + j*16 + colw] = acc[i*4+j][r]*sc;
    }
    #pragma unroll
    for (int rr8=0; rr8<8; rr8++){
      int row = rr8*4 + quad;
      float4 v = *(float4*)&eds[wave][row*64 + colw*4];
      int m = s*128 + wm*64 + ih*32 + row;
      int n = bn*128 + wn*64 + colw*4;
      *(float4*)&OG[(size_t)m*O_DIM + n] = v;
    }
  }
}

// Whole ov recurrence in ONE 512-thread block (256 VGPR/wave budget):
// ov[128]/thread; half-step-deep issue-before-consume pipeline (two 8xfloat4
// buffers); Q0 of t+1 issued before the reduction/spike tail so it flies
// through the serial section. Spikes emitted as 128-bit masks per thread.
__global__ __launch_bounds__(512) void ov_chain(const float* __restrict__ OG,
                                                unsigned* __restrict__ bits)
{
  __shared__ float red[8];
  __shared__ float svth;
  const int tid = threadIdx.x, lane = tid&63, wv = tid>>6;
  float ov[128];
  #pragma unroll
  for (int e=0;e<128;e++) ov[e]=0.f;

  const float* base = OG + tid*4;     // f4 index = q*512 + tid, q = 0..31
  float4 A[8], Bq[8];
  #pragma unroll
  for (int p=0;p<8;p++) A[p] = *(const float4*)(base + p*2048);   // Q0(t=0)

  for (int t=0;t<T_STEPS;t++){
    const float* cur = base + (size_t)t*65536;
    float lmax = -3.0e38f;
    // phase 0: issue Q1 -> Bq, consume A (Q0) -> ov[0..31]
    #pragma unroll
    for (int p=0;p<8;p++) Bq[p] = *(const float4*)(cur + (8+p)*2048);
    #pragma unroll
    for (int p=0;p<8;p++){
      int e = p*4;
      ov[e+0]+=A[p].x; ov[e+1]+=A[p].y; ov[e+2]+=A[p].z; ov[e+3]+=A[p].w;
      lmax = fmaxf(lmax, fmaxf(fmaxf(ov[e+0],ov[e+1]),fmaxf(ov[e+2],ov[e+3])));
    }
    // phase 1: issue Q2 -> A, consume Bq (Q1) -> ov[32..63]
    #pragma unroll
    for (int p=0;p<8;p++) A[p] = *(const float4*)(cur + (16+p)*2048);
    #pragma unroll
    for (int p=0;p<8;p++){
      int e = 32 + p*4;
      ov[e+0]+=Bq[p].x; ov[e+1]+=Bq[p].y; ov[e+2]+=Bq[p].z; ov[e+3]+=Bq[p].w;
      lmax = fmaxf(lmax, fmaxf(fmaxf(ov[e+0],ov[e+1]),fmaxf(ov[e+2],ov[e+3])));
    }
    // phase 2: issue Q3 -> Bq, consume A (Q2) -> ov[64..95]
    #pragma unroll
    for (int p=0;p<8;p++) Bq[p] = *(const float4*)(cur + (24+p)*2048);
    #pragma unroll
    for (int p=0;p<8;p++){
      int e = 64 + p*4;
      ov[e+0]+=A[p].x; ov[e+1]+=A[p].y; ov[e+2]+=A[p].z; ov[e+3]+=A[p].w;
      lmax = fmaxf(lmax, fmaxf(fmaxf(ov[e+0],ov[e+1]),fmaxf(ov[e+2],ov[e+3])));
    }
    // phase 3: issue Q0(t+1) -> A (flies through the serial tail), consume Bq (Q3)
    if (t+1 < T_STEPS){
      #pragma unroll
      for (int p=0;p<8;p++) A[p] = *(const float4*)(cur + 65536 + p*2048);
    }
    #pragma unroll
    for (int p=0;p<8;p++){
      int e = 96 + p*4;
      ov[e+0]+=Bq[p].x; ov[e+1]+=Bq[p].y; ov[e+2]+=Bq[p].z; ov[e+3]+=Bq[p].w;
      lmax = fmaxf(lmax, fmaxf(fmaxf(ov[e+0],ov[e+1]),fmaxf(ov[e+2],ov[e+3])));
    }
    // global (block) max -> dynamic threshold
    #pragma unroll
    for (int off=32; off>0; off>>=1) lmax = fmaxf(lmax, __shfl_down(lmax, off));
    if (lane==0) red[wv] = lmax;
    __syncthreads();
    if (tid==0){
      float m = red[0];
      #pragma unroll
      for (int w=1;w<8;w++) m = fmaxf(m, red[w]);
      svth = 0.3f * tanhf(0.3f * m);
    }
    __syncthreads();
    const float vt = svth;
    unsigned w0=0u, w1=0u, w2=0u, w3=0u;
    #pragma unroll
    for (int q=0;q<32;q++){
      unsigned* wp = (q<8)?&w0:(q<16)?&w1:(q<24)?&w2:&w3;
      #pragma unroll
      for (int c=0;c<4;c++){
        int e = q*4+c;
        bool os = ov[e] > vt;
        *wp |= os ? (1u<<((q&7)*4+c)) : 0u;
        ov[e] = os ? 0.f : 0.5f*ov[e];
      }
    }
    *(uint4*)(bits + ((size_t)t*512 + tid)*4) = make_uint4(w0,w1,w2,w3);
  }
}

// out[o] = sum over t of spike bit for element o.
__global__ __launch_bounds__(256) void count_kernel(const unsigned* __restrict__ bits,
                                                    float* __restrict__ out)
{
  const int o = blockIdx.x*256 + threadIdx.x;   // 0..65535
  const int f4 = o>>2, c = o&3;
  const int q = f4>>9, tid = f4&511;
  const int w = q>>3, pos = (q&7)*4 + c;
  const unsigned* src = bits + tid*4 + w;
  unsigned cnt=0;
  #pragma unroll 4
  for (int t=0;t<T_STEPS;t++) cnt += (src[(size_t)t*2048] >> pos) & 1u;
  out[o] = (float)cnt;
}

extern "C" void kernel_launch(void* const* d_in, const int* in_sizes, int n_in,
                              void* d_out, int out_size, void* d_ws, size_t ws_size,
                              hipStream_t stream) {
  const float* spike = (const float*)d_in[0];
  const float* Wh    = (const float*)d_in[5];   // [H, I]
  const float* Wo    = (const float*)d_in[6];   // [O, H]
  float* out = (float*)d_out;

  char* ws = (char*)d_ws;
  size_t off = 0;
  _Float16* XAhi = (_Float16*)(ws+off); off += (size_t)T_CHUNK*B_DIM*I_DIM*2;
  _Float16* XAlo = (_Float16*)(ws+off); off += (size_t)T_CHUNK*B_DIM*I_DIM*2;
  _Float16* WHhi = (_Float16*)(ws+off); off += (size_t)H_DIM*I_DIM*2;
  _Float16* WHlo = (_Float16*)(ws+off); off += (size_t)H_DIM*I_DIM*2;
  _Float16* WOhi = (_Float16*)(ws+off); off += (size_t)O_DIM*H_DIM*2;
  _Float16* WOlo = (_Float16*)(ws+off); off += (size_t)O_DIM*H_DIM*2;
  float* G  = (float*)(ws+off);         off += (size_t)T_CHUNK*B_DIM*H_DIM*4;
  float* hv = (float*)(ws+off);         off += (size_t)B_DIM*H_DIM*4;
  _Float16* HS = (_Float16*)(ws+off);   off += (size_t)HS_RING*HS_SLOT*2;
  float* OG = (float*)(ws+off);         off += (size_t)T_STEPS*B_DIM*O_DIM*4;
  unsigned* bits = (unsigned*)(ws+off); off += (size_t)T_STEPS*512*4*4;
  unsigned* hmaxA = (unsigned*)(ws+off); off += 128*4;
  (void)ws_size; (void)in_sizes; (void)n_in; (void)out_size;

  init_kernel<<<(B_DIM*H_DIM+255)/256, 256, 0, stream>>>(hv, hmaxA);
  prep_w<<<256, 256, 0, stream>>>(Wh, WHhi, WHlo);
  prep_wo<<<32, 256, 0, stream>>>(Wo, WOhi, WOlo);

  for (int c = 0; c < T_STEPS/T_CHUNK; c++){
    prep_x<<<dim3(8,32,2), 256, 0, stream>>>(spike, XAhi, XAlo, c*T_CHUNK);
    gemm1_mfma<<<dim3(32, T_CHUNK), 256, 0, stream>>>(XAhi, XAlo, WHhi, WHlo, G);
    for (int j = 0; j < T_CHUNK; j++){
      int t = c*T_CHUNK + j;
      int ring = (t == 0) ? (HS_RING-1) : ((t-1) % HS_RING);
      hv_step<<<512, 256, 0, stream>>>(
          G + (size_t)j*B_DIM*H_DIM, hv, HS + (size_t)ring*HS_SLOT,
          hmaxA + t, hmaxA + t + 1, t);
      if (j == 0 && c > 0)
        gemm2_mfma<<<dim3(4, T_CHUNK), 256, 0, stream>>>(HS, WOhi, WOlo, OG, c-1);
    }
  }
  // hs_99 tail (t=100: emit-only), then last gemm2 chunk, then the ov chain.
  hv_step<<<512, 256, 0, stream>>>(
      G, hv, HS + (size_t)((T_STEPS-1) % HS_RING)*HS_SLOT,
      hmaxA + T_STEPS, hmaxA + T_STEPS, T_STEPS);
  gemm2_mfma<<<dim3(4, T_CHUNK), 256, 0, stream>>>(HS, WOhi, WOlo, OG, T_STEPS/T_CHUNK - 1);
  ov_chain<<<1, 512, 0, stream>>>(OG, bits);
  count_kernel<<<256, 256, 0, stream>>>(bits, out);
}

// Round 8
// 2249.411 us; speedup vs baseline: 3.4326x; 1.2066x over previous
//
#include <hip/hip_runtime.h>
#include <math.h>
#include <stdint.h>

#define T_STEPS 100
#define B_DIM 128
#define I_DIM 1024
#define H_DIM 4096
#define O_DIM 512
#define T_CHUNK 20
#define HS_RING 21
#define HS_SLOT ((size_t)8*128*512)   // f16 per t-slot (8 m16-tiles x 128 kc x 512)

typedef _Float16 f16x8 __attribute__((ext_vector_type(8)));
typedef _Float16 f16x4 __attribute__((ext_vector_type(4)));
typedef float    f32x4 __attribute__((ext_vector_type(4)));

#define AS1 __attribute__((address_space(1)))
#define AS3 __attribute__((address_space(3)))

// Async global->LDS, 16B/lane. LDS dest is wave-uniform base + lane*16 (m104),
// which exactly matches the 1KB fragment-block layout (64 lanes x 16B).
__device__ __forceinline__ void gload_lds16(const _Float16* g, _Float16* l){
  __builtin_amdgcn_global_load_lds(
      (const AS1 unsigned*)(uintptr_t)g,
      (AS3 unsigned*)(unsigned)(uintptr_t)l, 16, 0, 0);
}

__device__ __forceinline__ unsigned fmap(float f){
  unsigned u = __float_as_uint(f);
  return (u & 0x80000000u) ? ~u : (u | 0x80000000u);
}
__device__ __forceinline__ float funmap(unsigned m){
  unsigned u = (m & 0x80000000u) ? (m & 0x7FFFFFFFu) : ~m;
  return __uint_as_float(u);
}
__device__ __forceinline__ float vth_of(unsigned m){
  return 0.3f * tanhf(0.3f * funmap(m));
}

__global__ __launch_bounds__(256) void init_kernel(float* hv, unsigned* hmaxA)
{
  int i = blockIdx.x * 256 + threadIdx.x;
  if (i < B_DIM*H_DIM) hv[i] = 0.f;
  if (i < 128) hmaxA[i] = (i==0) ? 0x80000000u : fmap(-3.0e38f); // slot0 = max(0)
}

// spike_data [B][I][T] fp32 -> fragment-tiled f16 hi/lo of (x*2048), chunk of 20 t.
__global__ __launch_bounds__(256) void prep_x(const float* __restrict__ sp,
                                              _Float16* __restrict__ Ahi,
                                              _Float16* __restrict__ Alo, int t0)
{
  __shared__ float tile[32][16][10];
  const int b16 = blockIdx.x, kc = blockIdx.y, tz = blockIdx.z;
  for (int e = threadIdx.x; e < 5120; e += 256){
    int tt = e % 10, row = e / 10;
    int bb = row >> 5, ii = row & 31;
    tile[ii][bb][tt] =
      sp[((size_t)(b16*16+bb)*I_DIM + kc*32 + ii)*T_STEPS + t0 + tz*10 + tt];
  }
  __syncthreads();
  for (int u = threadIdx.x; u < 640; u += 256){
    int tl = u >> 6, l = u & 63, kg = l >> 4, r = l & 15;
    f16x8 hi, lo;
    #pragma unroll
    for (int e=0;e<8;e++){
      float x = tile[kg*8+e][r][tl] * 2048.f;
      _Float16 h = (_Float16)x;
      hi[e] = h;
      lo[e] = (_Float16)(x - (float)h);
    }
    int t_local = tz*10 + tl;
    size_t off = ((size_t)(t_local*8 + b16)*32 + kc)*512 + kg*128 + r*8;
    *(f16x8*)(Ahi + off) = hi;
    *(f16x8*)(Alo + off) = lo;
  }
}

// Wh [H][I] fp32 -> FB-tiled f16 hi/lo of (w*256).
__global__ __launch_bounds__(256) void prep_w(const float* __restrict__ Wh,
                                              _Float16* __restrict__ Bhi,
                                              _Float16* __restrict__ Blo)
{
  const int n16 = blockIdx.x;
  for (int u = threadIdx.x; u < 2048; u += 256){
    int kc = u >> 6, l = u & 63, kg = l >> 4, r = l & 15;
    const float* src = Wh + (size_t)(n16*16 + r)*I_DIM + kc*32 + kg*8;
    f16x8 hi, lo;
    #pragma unroll
    for (int e=0;e<8;e++){
      float x = src[e] * 256.f;
      _Float16 h = (_Float16)x;
      hi[e] = h;
      lo[e] = (_Float16)(x - (float)h);
    }
    size_t off = ((size_t)n16*32 + kc)*512 + kg*128 + r*8;
    *(f16x8*)(Bhi + off) = hi;
    *(f16x8*)(Blo + off) = lo;
  }
}

// Wo [O][H] fp32 -> FB-tiled f16 hi/lo of (w*256). 128 kc over H.
__global__ __launch_bounds__(256) void prep_wo(const float* __restrict__ Wo,
                                               _Float16* __restrict__ Bhi,
                                               _Float16* __restrict__ Blo)
{
  const int n16 = blockIdx.x;   // 0..31
  for (int u = threadIdx.x; u < 8192; u += 256){
    int kc = u >> 6, l = u & 63, kg = l >> 4, r = l & 15;
    const float* src = Wo + (size_t)(n16*16 + r)*H_DIM + kc*32 + kg*8;
    f16x8 hi, lo;
    #pragma unroll
    for (int e=0;e<8;e++){
      float x = src[e] * 256.f;
      _Float16 h = (_Float16)x;
      hi[e] = h;
      lo[e] = (_Float16)(x - (float)h);
    }
    size_t off = ((size_t)(n16*128 + kc))*512 + kg*128 + r*8;
    *(f16x8*)(Bhi + off) = hi;
    *(f16x8*)(Blo + off) = lo;
  }
}

// Batched GEMM1 (chunk of 20 t): G = XT @ Wh^T via fp16x3 exact-split MFMA.
// K-loop: async global_load_lds double-buffer, ONE barrier per kc (m97 form).
__global__ __launch_bounds__(256, 2) void gemm1_mfma(
    const _Float16* __restrict__ Ahi, const _Float16* __restrict__ Alo,
    const _Float16* __restrict__ Bhi, const _Float16* __restrict__ Blo,
    float* __restrict__ G)
{
  __shared__ __align__(16) _Float16 lds[2][4][8][512];   // 64 KB, 2 blocks/CU
  const int tid = threadIdx.x, wave = tid>>6, lane = tid&63;
  const int bn = blockIdx.x, bm = blockIdx.y;
  const int wm = wave>>1, wn = wave&1;

  const _Float16* srcbase = (wave==0)?Ahi:(wave==1)?Alo:(wave==2)?Bhi:Blo;
  const int r16b = ((wave<2) ? bm : bn)*8;
  const _Float16* gsrc = srcbase + (size_t)r16b*32*512 + lane*8;

  f32x4 acc[16];
  #pragma unroll
  for (int i=0;i<16;i++) acc[i] = (f32x4){0.f,0.f,0.f,0.f};

  // stage kc=0 into buffer 0
  #pragma unroll
  for (int q=0;q<8;q++)
    gload_lds16(gsrc + (size_t)q*32*512, &lds[0][wave][q][0]);

  for (int kc=0;kc<32;kc++){
    __syncthreads();              // vmcnt(0) drain + barrier: buf[kc&1] ready
    if (kc < 31){                 // async prefetch kc+1; flies during compute
      #pragma unroll
      for (int q=0;q<8;q++)
        gload_lds16(gsrc + ((size_t)q*32 + kc+1)*512, &lds[(kc+1)&1][wave][q][0]);
    }
    const int cb = kc&1;
    f16x8 fAh[4], fAl[4], fBh[4], fBl[4];
    #pragma unroll
    for (int i=0;i<4;i++){
      fAh[i] = *(const f16x8*)&lds[cb][0][wm*4+i][lane*8];
      fAl[i] = *(const f16x8*)&lds[cb][1][wm*4+i][lane*8];
      fBh[i] = *(const f16x8*)&lds[cb][2][wn*4+i][lane*8];
      fBl[i] = *(const f16x8*)&lds[cb][3][wn*4+i][lane*8];
    }
    #pragma unroll
    for (int i=0;i<4;i++)
      #pragma unroll
      for (int j=0;j<4;j++)
        acc[i*4+j] = __builtin_amdgcn_mfma_f32_16x16x32_f16(fAh[i], fBh[j], acc[i*4+j], 0,0,0);
    #pragma unroll
    for (int i=0;i<4;i++)
      #pragma unroll
      for (int j=0;j<4;j++)
        acc[i*4+j] = __builtin_amdgcn_mfma_f32_16x16x32_f16(fAh[i], fBl[j], acc[i*4+j], 0,0,0);
    #pragma unroll
    for (int i=0;i<4;i++)
      #pragma unroll
      for (int j=0;j<4;j++)
        acc[i*4+j] = __builtin_amdgcn_mfma_f32_16x16x32_f16(fAl[i], fBh[j], acc[i*4+j], 0,0,0);
  }
  const int colw = lane&15, quad = lane>>4;
  const float sc = 1.f/(2048.f*256.f);
  float* eds = (float*)lds + wave*2048;
  __syncthreads();
  #pragma unroll
  for (int ih=0; ih<2; ih++){
    #pragma unroll
    for (int il=0; il<2; il++){
      int i = ih*2+il;
      #pragma unroll
      for (int j=0;j<4;j++)
        #pragma unroll
        for (int r=0;r<4;r++)
          eds[(il*16 + quad*4 + r)*64 + j*16 + colw] = acc[i*4+j][r]*sc;
    }
    #pragma unroll
    for (int rr8=0; rr8<8; rr8++){
      int row = rr8*4 + quad;
      float4 v = *(float4*)&eds[row*64 + colw*4];
      int m = bm*128 + wm*64 + ih*32 + row;
      int n = bn*128 + wn*64 + colw*4;
      *(float4*)&G[(size_t)m*H_DIM + n] = v;
    }
  }
}

// Sequential hv step t: emits hs_{t-1} (f16, fragment-tiled into ring slot),
// then hv_t = (hv>vth?0:0.5hv) + G_t, block max -> hmaxA[t+1].
__global__ __launch_bounds__(256) void hv_step(
    const float* __restrict__ Gs, float* __restrict__ hv,
    _Float16* __restrict__ hs_slot,
    const unsigned* __restrict__ hmax_t, unsigned* __restrict__ hmax_n, int t)
{
  __shared__ float red[256];
  const int tid = threadIdx.x;
  const int gid = blockIdx.x*256 + tid;     // 0..131071 (f4 index)
  const int b = gid >> 10, h0 = (gid & 1023) << 2;
  const float vth = vth_of(*hmax_t);
  float4 h = *(const float4*)(hv + (size_t)gid*4);

  if (t > 0){   // hs_{t-1} = hv_{t-1} > vth(max hv_{t-1})
    const int kc = h0>>5, kg=(h0>>3)&3, e=h0&7, r=b&15, m16l=b>>4;
    f16x4 s;
    s[0]=(h.x>vth)?(_Float16)1:(_Float16)0; s[1]=(h.y>vth)?(_Float16)1:(_Float16)0;
    s[2]=(h.z>vth)?(_Float16)1:(_Float16)0; s[3]=(h.w>vth)?(_Float16)1:(_Float16)0;
    *(f16x4*)(hs_slot + ((size_t)m16l*128 + kc)*512 + kg*128 + r*8 + e) = s;
  }
  if (t < T_STEPS){
    float4 g = *(const float4*)(Gs + (size_t)gid*4);
    float4 o;
    o.x = (h.x>vth ? 0.f : 0.5f*h.x) + g.x;
    o.y = (h.y>vth ? 0.f : 0.5f*h.y) + g.y;
    o.z = (h.z>vth ? 0.f : 0.5f*h.z) + g.z;
    o.w = (h.w>vth ? 0.f : 0.5f*h.w) + g.w;
    *(float4*)(hv + (size_t)gid*4) = o;
    red[tid] = fmaxf(fmaxf(o.x,o.y),fmaxf(o.z,o.w));
    __syncthreads();
    for (int s2=128;s2>0;s2>>=1){ if (tid<s2) red[tid]=fmaxf(red[tid],red[tid+s2]); __syncthreads(); }
    if (tid==0) atomicMax(hmax_n, fmap(red[0]));
  }
}

// Batched GEMM2 for one chunk: OG[s] = HS[s] @ Wo^T (A exact f16, B hi/lo).
__global__ __launch_bounds__(256) void gemm2_mfma(
    const _Float16* __restrict__ HS,
    const _Float16* __restrict__ WoHi, const _Float16* __restrict__ WoLo,
    float* __restrict__ OG, int c)
{
  __shared__ float eds[4][2048];
  const int tid = threadIdx.x, wave = tid>>6, lane = tid&63;
  const int bn = blockIdx.x, bm = blockIdx.y;
  const int s = c*T_CHUNK + bm, ring = s % HS_RING;
  const int wm = wave>>1, wn = wave&1;

  const _Float16* Ab  = HS + ((size_t)(ring*8 + wm*4)*128)*512 + lane*8;
  const _Float16* Bhb = WoHi + ((size_t)(bn*8 + wn*4)*128)*512 + lane*8;
  const _Float16* Blb = WoLo + ((size_t)(bn*8 + wn*4)*128)*512 + lane*8;

  f32x4 acc[16];
  #pragma unroll
  for (int i=0;i<16;i++) acc[i] = (f32x4){0.f,0.f,0.f,0.f};

  int4 ra[4], rh[4], rl[4];
  #pragma unroll
  for (int q=0;q<4;q++){
    ra[q] = *(const int4*)(Ab  + (size_t)q*128*512);
    rh[q] = *(const int4*)(Bhb + (size_t)q*128*512);
    rl[q] = *(const int4*)(Blb + (size_t)q*128*512);
  }
  for (int kc=0;kc<128;kc++){
    f16x8 fA[4], fH[4], fL[4];
    #pragma unroll
    for (int q=0;q<4;q++){
      fA[q] = *(f16x8*)&ra[q]; fH[q] = *(f16x8*)&rh[q]; fL[q] = *(f16x8*)&rl[q];
    }
    if (kc < 127){
      #pragma unroll
      for (int q=0;q<4;q++){
        ra[q] = *(const int4*)(Ab  + ((size_t)q*128 + kc+1)*512);
        rh[q] = *(const int4*)(Bhb + ((size_t)q*128 + kc+1)*512);
        rl[q] = *(const int4*)(Blb + ((size_t)q*128 + kc+1)*512);
      }
    }
    #pragma unroll
    for (int i=0;i<4;i++)
      #pragma unroll
      for (int j=0;j<4;j++)
        acc[i*4+j] = __builtin_amdgcn_mfma_f32_16x16x32_f16(fA[i], fH[j], acc[i*4+j], 0,0,0);
    #pragma unroll
    for (int i=0;i<4;i++)
      #pragma unroll
      for (int j=0;j<4;j++)
        acc[i*4+j] = __builtin_amdgcn_mfma_f32_16x16x32_f16(fA[i], fL[j], acc[i*4+j], 0,0,0);
  }
  const int colw = lane&15, quad = lane>>4;
  const float sc = 1.f/256.f;
  #pragma unroll
  for (int ih=0; ih<2; ih++){
    #pragma unroll
    for (int il=0; il<2; il++){
      int i = ih*2+il;
      #pragma unroll
      for (int j=0;j<4;j++)
        #pragma unroll
        for (int r=0;r<4;r++)
          eds[wave][(il*16 + quad*4 + r)*64 + j*16 + colw] = acc[i*4+j][r]*sc;
    }
    #pragma unroll
    for (int rr8=0; rr8<8; rr8++){
      int row = rr8*4 + quad;
      float4 v = *(float4*)&eds[wave][row*64 + colw*4];
      int m = s*128 + wm*64 + ih*32 + row;
      int n = bn*128 + wn*64 + colw*4;
      *(float4*)&OG[(size_t)m*O_DIM + n] = v;
    }
  }
}

// Whole ov recurrence in ONE 1024-thread block. __launch_bounds__(1024,4)
// -> 16 waves = 1 block/CU -> 128 VGPR/wave cap: ov[64] + 2x(4xfloat4)
// pipeline buffers + temps ~ 110 VGPR, NO scratch spill (R6/R7 both spilled:
// VGPR_Count 64/128 < needed state; spill round-trips L2 every step).
__global__ __launch_bounds__(1024, 4) void ov_chain(const float* __restrict__ OG,
                                                    unsigned* __restrict__ bits)
{
  __shared__ float red[16];
  __shared__ float svth;
  const int tid = threadIdx.x, lane = tid&63, wv = tid>>6;
  float ov[64];
  #pragma unroll
  for (int e=0;e<64;e++) ov[e]=0.f;

  const float* base = OG + tid*4;      // slice layout: float4 idx = q*1024+tid
  float4 A[4], Bq[4];
  #pragma unroll
  for (int p=0;p<4;p++) A[p] = *(const float4*)(base + p*4096);  // Q0 of t=0

  for (int t=0;t<T_STEPS;t++){
    const float* cur = base + (size_t)t*65536;
    float lmax = -3.0e38f;
    // phase 0: issue Q1 -> Bq, consume A (Q0)
    #pragma unroll
    for (int p=0;p<4;p++) Bq[p] = *(const float4*)(cur + (4+p)*4096);
    #pragma unroll
    for (int p=0;p<4;p++){
      int e = p*4;
      ov[e+0]+=A[p].x; ov[e+1]+=A[p].y; ov[e+2]+=A[p].z; ov[e+3]+=A[p].w;
      lmax = fmaxf(lmax, fmaxf(fmaxf(ov[e+0],ov[e+1]),fmaxf(ov[e+2],ov[e+3])));
    }
    // phase 1: issue Q2 -> A, consume Bq (Q1)
    #pragma unroll
    for (int p=0;p<4;p++) A[p] = *(const float4*)(cur + (8+p)*4096);
    #pragma unroll
    for (int p=0;p<4;p++){
      int e = 16 + p*4;
      ov[e+0]+=Bq[p].x; ov[e+1]+=Bq[p].y; ov[e+2]+=Bq[p].z; ov[e+3]+=Bq[p].w;
      lmax = fmaxf(lmax, fmaxf(fmaxf(ov[e+0],ov[e+1]),fmaxf(ov[e+2],ov[e+3])));
    }
    // phase 2: issue Q3 -> Bq, consume A (Q2)
    #pragma unroll
    for (int p=0;p<4;p++) Bq[p] = *(const float4*)(cur + (12+p)*4096);
    #pragma unroll
    for (int p=0;p<4;p++){
      int e = 32 + p*4;
      ov[e+0]+=A[p].x; ov[e+1]+=A[p].y; ov[e+2]+=A[p].z; ov[e+3]+=A[p].w;
      lmax = fmaxf(lmax, fmaxf(fmaxf(ov[e+0],ov[e+1]),fmaxf(ov[e+2],ov[e+3])));
    }
    // phase 3: issue Q0(t+1) -> A (flies through the serial tail), consume Bq (Q3)
    if (t+1 < T_STEPS){
      #pragma unroll
      for (int p=0;p<4;p++) A[p] = *(const float4*)(cur + 65536 + p*4096);
    }
    #pragma unroll
    for (int p=0;p<4;p++){
      int e = 48 + p*4;
      ov[e+0]+=Bq[p].x; ov[e+1]+=Bq[p].y; ov[e+2]+=Bq[p].z; ov[e+3]+=Bq[p].w;
      lmax = fmaxf(lmax, fmaxf(fmaxf(ov[e+0],ov[e+1]),fmaxf(ov[e+2],ov[e+3])));
    }
    // block max -> dynamic threshold
    #pragma unroll
    for (int off=32; off>0; off>>=1) lmax = fmaxf(lmax, __shfl_down(lmax, off));
    if (lane==0) red[wv] = lmax;
    __syncthreads();
    if (tid==0){
      float m = red[0];
      #pragma unroll
      for (int w=1;w<16;w++) m = fmaxf(m, red[w]);
      svth = 0.3f * tanhf(0.3f * m);
    }
    __syncthreads();
    const float vt = svth;
    unsigned b0=0u, b1=0u;
    #pragma unroll
    for (int e=0;e<32;e++){
      bool os = ov[e] > vt;
      b0 |= os ? (1u<<e) : 0u;
      ov[e] = os ? 0.f : 0.5f*ov[e];
    }
    #pragma unroll
    for (int e=32;e<64;e++){
      bool os = ov[e] > vt;
      b1 |= os ? (1u<<(e-32)) : 0u;
      ov[e] = os ? 0.f : 0.5f*ov[e];
    }
    uint2 bv; bv.x=b0; bv.y=b1;
    *(uint2*)(bits + ((size_t)t*1024 + tid)*2) = bv;
  }
}

// out[o] = sum over t of spike bit for element o.
__global__ __launch_bounds__(256) void count_kernel(const unsigned* __restrict__ bits,
                                                    float* __restrict__ out)
{
  const int o = blockIdx.x*256 + threadIdx.x;   // 0..65535
  const int f4 = o>>2, c = o&3;
  const int q = f4>>10, tid = f4&1023;
  const int b = q*4 + c, w = b>>5, pos = b&31;
  const unsigned* src = bits + tid*2 + w;
  unsigned cnt=0;
  #pragma unroll 4
  for (int t=0;t<T_STEPS;t++) cnt += (src[(size_t)t*2048] >> pos) & 1u;
  out[o] = (float)cnt;
}

extern "C" void kernel_launch(void* const* d_in, const int* in_sizes, int n_in,
                              void* d_out, int out_size, void* d_ws, size_t ws_size,
                              hipStream_t stream) {
  const float* spike = (const float*)d_in[0];
  const float* Wh    = (const float*)d_in[5];   // [H, I]
  const float* Wo    = (const float*)d_in[6];   // [O, H]
  float* out = (float*)d_out;

  char* ws = (char*)d_ws;
  size_t off = 0;
  _Float16* XAhi = (_Float16*)(ws+off); off += (size_t)T_CHUNK*B_DIM*I_DIM*2;
  _Float16* XAlo = (_Float16*)(ws+off); off += (size_t)T_CHUNK*B_DIM*I_DIM*2;
  _Float16* WHhi = (_Float16*)(ws+off); off += (size_t)H_DIM*I_DIM*2;
  _Float16* WHlo = (_Float16*)(ws+off); off += (size_t)H_DIM*I_DIM*2;
  _Float16* WOhi = (_Float16*)(ws+off); off += (size_t)O_DIM*H_DIM*2;
  _Float16* WOlo = (_Float16*)(ws+off); off += (size_t)O_DIM*H_DIM*2;
  float* G  = (float*)(ws+off);         off += (size_t)T_CHUNK*B_DIM*H_DIM*4;
  float* hv = (float*)(ws+off);         off += (size_t)B_DIM*H_DIM*4;
  _Float16* HS = (_Float16*)(ws+off);   off += (size_t)HS_RING*HS_SLOT*2;
  float* OG = (float*)(ws+off);         off += (size_t)T_STEPS*B_DIM*O_DIM*4;
  unsigned* bits = (unsigned*)(ws+off); off += (size_t)T_STEPS*1024*2*4;
  unsigned* hmaxA = (unsigned*)(ws+off); off += 128*4;
  (void)ws_size; (void)in_sizes; (void)n_in; (void)out_size;

  init_kernel<<<(B_DIM*H_DIM+255)/256, 256, 0, stream>>>(hv, hmaxA);
  prep_w<<<256, 256, 0, stream>>>(Wh, WHhi, WHlo);
  prep_wo<<<32, 256, 0, stream>>>(Wo, WOhi, WOlo);

  for (int c = 0; c < T_STEPS/T_CHUNK; c++){
    prep_x<<<dim3(8,32,2), 256, 0, stream>>>(spike, XAhi, XAlo, c*T_CHUNK);
    gemm1_mfma<<<dim3(32, T_CHUNK), 256, 0, stream>>>(XAhi, XAlo, WHhi, WHlo, G);
    for (int j = 0; j < T_CHUNK; j++){
      int t = c*T_CHUNK + j;
      int ring = (t == 0) ? (HS_RING-1) : ((t-1) % HS_RING);
      hv_step<<<512, 256, 0, stream>>>(
          G + (size_t)j*B_DIM*H_DIM, hv, HS + (size_t)ring*HS_SLOT,
          hmaxA + t, hmaxA + t + 1, t);
      if (j == 0 && c > 0)
        gemm2_mfma<<<dim3(4, T_CHUNK), 256, 0, stream>>>(HS, WOhi, WOlo, OG, c-1);
    }
  }
  // hs_99 tail (t=100: emit-only), then last gemm2 chunk, then the ov chain.
  hv_step<<<512, 256, 0, stream>>>(
      G, hv, HS + (size_t)((T_STEPS-1) % HS_RING)*HS_SLOT,
      hmaxA + T_STEPS, hmaxA + T_STEPS, T_STEPS);
  gemm2_mfma<<<dim3(4, T_CHUNK), 256, 0, stream>>>(HS, WOhi, WOlo, OG, T_STEPS/T_CHUNK - 1);
  ov_chain<<<1, 1024, 0, stream>>>(OG, bits);
  count_kernel<<<256, 256, 0, stream>>>(bits, out);
}